// Round 4
// baseline (405.047 us; speedup 1.0000x reference)
//
#include <hip/hip_runtime.h>
#include <stdint.h>

#define NN 8192
#define NF 512
#define NH 256

typedef __bf16 bf16_t;
typedef bf16_t bf16x8 __attribute__((ext_vector_type(8)));
typedef float f32x4 __attribute__((ext_vector_type(4)));
typedef float f32x16 __attribute__((ext_vector_type(16)));
typedef int i32x4 __attribute__((ext_vector_type(4)));
typedef int i32x8 __attribute__((ext_vector_type(8)));

// round-to-nearest-even f32 -> bf16 bit pattern
__device__ __forceinline__ unsigned short f2bf(float f) {
  union { float f; unsigned u; } v; v.f = f;
  unsigned r = v.u + 0x7FFFu + ((v.u >> 16) & 1u);
  return (unsigned short)(r >> 16);
}

// f32 -> OCP e4m3fn, RTNE, saturate to 448 (no NaN/Inf in our data)
__device__ __forceinline__ unsigned char f2fp8(float f) {
  union { float f; unsigned u; } v; v.f = f;
  const unsigned s = (v.u >> 24) & 0x80u;
  unsigned au = v.u & 0x7FFFFFFFu;
  if (au > 0x43E00000u) au = 0x43E00000u; // clamp |f| <= 448
  unsigned b;
  if (au < 0x3C800000u) { // |f| < 2^-6 : denormal, step 2^-9
    union { unsigned u; float f; } a; a.u = au;
    b = (unsigned)__float2int_rn(a.f * 512.0f); // 0..8
  } else {
    unsigned r = au + 0x0007FFFFu + ((au >> 20) & 1u); // RTNE keep bits>=20
    b = (r >> 20) - 960u; // (exp<<3|m3) - (120<<3); 448 -> 126
  }
  return (unsigned char)(s | b);
}

// OCP e4m3fn -> f32
__device__ __forceinline__ float fp8tof(unsigned u8) {
  const unsigned e = (u8 >> 3) & 0xFu, m = u8 & 7u;
  const unsigned sgn = (u8 & 0x80u) << 24;
  union { unsigned u; float f; } r;
  if (e == 0) {
    r.f = (float)m * 0.001953125f; // m * 2^-9
    r.u |= sgn;
  } else {
    r.u = sgn | ((e + 120u) << 23) | (m << 20);
  }
  return r.f;
}

// async global->LDS, 16B per lane; LDS dest is wave-uniform base + lane*16
__device__ __forceinline__ void gload16(const void* g, void* l) {
  __builtin_amdgcn_global_load_lds(
      (__attribute__((address_space(1))) void*)g,
      (__attribute__((address_space(3))) void*)l, 16, 0, 0);
}

// ---- fused: A8 = fp8(adj) raw cast AND dinv = rsqrt(max(rowsum,1e-12)) ----
__global__ void castadj_deg_kernel(const float* __restrict__ adj,
                                   unsigned char* __restrict__ A8,
                                   float* __restrict__ dinv) {
  const int i = blockIdx.x, t = threadIdx.x;
  const float4* row = reinterpret_cast<const float4*>(adj + (long)i * NN);
  uint4* orow = reinterpret_cast<uint4*>(A8 + (long)i * NN);
  float s = 0.f;
#pragma unroll
  for (int it = 0; it < 2; ++it) {
    unsigned pk[4];
#pragma unroll
    for (int q = 0; q < 4; ++q) {
      float4 a = row[it * 1024 + t * 4 + q];
      s += a.x + a.y + a.z + a.w;
      pk[q] = (unsigned)f2fp8(a.x) | ((unsigned)f2fp8(a.y) << 8) |
              ((unsigned)f2fp8(a.z) << 16) | ((unsigned)f2fp8(a.w) << 24);
    }
    orow[it * 256 + t] = make_uint4(pk[0], pk[1], pk[2], pk[3]);
  }
  for (int o = 32; o; o >>= 1) s += __shfl_down(s, o, 64);
  __shared__ float sm[4];
  if ((t & 63) == 0) sm[t >> 6] = s;
  __syncthreads();
  if (t == 0) {
    float d = fmaxf(sm[0] + sm[1] + sm[2] + sm[3], 1e-12f);
    dinv[i] = rsqrtf(d);
  }
}

// -------- cast x -> Acomb cols [0,512) bf16; yT = fp8(64*dinv .* x)^T --------
__global__ void castx_kernel(const float* __restrict__ x, const float* __restrict__ dinv,
                             unsigned char* __restrict__ yT,
                             unsigned short* __restrict__ Acomb) {
  __shared__ float tile[64][65];
  const int c0 = blockIdx.x * 64; // feature base
  const int r0 = blockIdx.y * 64; // node base
  const int t = threadIdx.x;
#pragma unroll
  for (int it = 0; it < 16; ++it) {
    int e = it * 256 + t;
    int r = e >> 6, c = e & 63;
    float v = x[(long)(r0 + r) * NF + c0 + c];
    tile[r][c] = v;
    Acomb[(long)(r0 + r) * 1536 + c0 + c] = f2bf(v);
  }
  __syncthreads();
#pragma unroll
  for (int it = 0; it < 16; ++it) {
    int e = it * 256 + t;
    int rr = e >> 6, cc = e & 63;
    const int node = r0 + cc;
    yT[(long)(c0 + rr) * NN + node] = f2fp8(tile[cc][rr] * (64.f * dinv[node]));
  }
}

// -------- cast cheb_W [1536,256] -> WcT [256][1536] bf16 --------
__global__ void castw_kernel(const float* __restrict__ W, unsigned short* __restrict__ WT) {
  __shared__ float tile[64][65];
  const int c0 = blockIdx.x * 64; // n base (0..255)
  const int r0 = blockIdx.y * 64; // k base (0..1535)
  const int t = threadIdx.x;
#pragma unroll
  for (int it = 0; it < 16; ++it) {
    int e = it * 256 + t;
    int r = e >> 6, c = e & 63;
    tile[r][c] = W[(long)(r0 + r) * NH + c0 + c];
  }
  __syncthreads();
#pragma unroll
  for (int it = 0; it < 16; ++it) {
    int e = it * 256 + t;
    int rr = e >> 6, cc = e & 63;
    WT[(long)(c0 + rr) * 1536 + r0 + cc] = f2bf(tile[cc][rr]);
  }
}

// read a 32-byte (8-dword) fp8 fragment from the XOR-swizzled LDS tile
__device__ __forceinline__ i32x8 frag32(const unsigned char* Ls, int row, int base) {
  const int sw = (row & 7) << 4;
  const i32x4 lo = *reinterpret_cast<const i32x4*>(&Ls[row * 128 + (base ^ sw)]);
  const i32x4 hi = *reinterpret_cast<const i32x4*>(&Ls[row * 128 + ((base + 16) ^ sw)]);
  i32x8 r;
  r[0] = lo[0]; r[1] = lo[1]; r[2] = lo[2]; r[3] = lo[3];
  r[4] = hi[0]; r[5] = hi[1]; r[6] = hi[2]; r[7] = hi[3];
  return r;
}

// ---------------- MX-fp8 MFMA partial GEMM, P[kz] = A[:,krange] @ B[krange,:] ----------------
// 128x128 tile, BK=128 fp8 bytes, 4 waves (2x2), each wave 64x64 via 2x2 frags of 32x32x64.
// B given as BT [N][K] fp8. Unit scales (0x7F = 2^0). LDS XOR-swizzled via pre-swizzled
// global source (linear gload_lds dest) + matching XOR on ds_read (rule #21).
__global__ __launch_bounds__(256) void gemm_fp8(
    const unsigned char* __restrict__ A, const unsigned char* __restrict__ BT,
    const int lda, const int ldbt, const int kLen, const int Nout,
    float* __restrict__ P) {
  __shared__ unsigned char As[128 * 128];
  __shared__ unsigned char Bs[128 * 128];
  const int tid = threadIdx.x;
  const int w = tid >> 6, l = tid & 63;
  const int wr = w >> 1, wc = w & 1;
  // XCD-aware swizzle (nwg2d multiple of 8 for our grids)
  const int nwg2d = gridDim.x * gridDim.y;
  const int lin = blockIdx.x + gridDim.x * blockIdx.y;
  const int wg = (lin & 7) * (nwg2d >> 3) + (lin >> 3);
  const int bx = wg % gridDim.x, by = wg / gridDim.x;
  const int aRow0 = by * 128, bRow0 = bx * 128;
  const long kbeg = (long)blockIdx.z * kLen;
  const int srow = l >> 3;                 // row within 8-row chunk
  const int scol = 16 * ((l & 7) ^ srow);  // pre-swizzled source column byte
  f32x16 acc[2][2] = {};

  for (int k0 = 0; k0 < kLen; k0 += 128) {
    __syncthreads();
#pragma unroll
    for (int i = 0; i < 4; ++i) {
      const int ch = w * 4 + i; // chunk 0..15: 8 rows x 128 k-bytes (1024B)
      gload16(A + (long)(aRow0 + ch * 8 + srow) * lda + kbeg + k0 + scol, &As[ch * 1024]);
      gload16(BT + (long)(bRow0 + ch * 8 + srow) * ldbt + kbeg + k0 + scol, &Bs[ch * 1024]);
    }
    __syncthreads(); // vmcnt(0) drained before s_barrier -> LDS valid
#pragma unroll
    for (int g = 0; g < 2; ++g) {
      const int kb = g * 64 + (l >> 5) * 32;
      i32x8 af[2], bf[2];
#pragma unroll
      for (int m = 0; m < 2; ++m)
        af[m] = frag32(As, wr * 64 + m * 32 + (l & 31), kb);
#pragma unroll
      for (int n = 0; n < 2; ++n)
        bf[n] = frag32(Bs, wc * 64 + n * 32 + (l & 31), kb);
#pragma unroll
      for (int m = 0; m < 2; ++m)
#pragma unroll
        for (int n = 0; n < 2; ++n)
          acc[m][n] = __builtin_amdgcn_mfma_scale_f32_32x32x64_f8f6f4(
              af[m], bf[n], acc[m][n], 0, 0, 0, 0x7F7F7F7F, 0, 0x7F7F7F7F);
    }
  }

  // C/D 32x32 map: col = lane&31, row = (reg&3) + 8*(reg>>2) + 4*(lane>>5)
  float* Pk = P + (long)blockIdx.z * NN * Nout;
  const int colb = bRow0 + wc * 64 + (l & 31);
  const int rbase = aRow0 + wr * 64 + 4 * (l >> 5);
#pragma unroll
  for (int m = 0; m < 2; ++m)
#pragma unroll
    for (int n = 0; n < 2; ++n)
#pragma unroll
      for (int reg = 0; reg < 16; ++reg) {
        const int row = rbase + m * 32 + (reg & 3) + 8 * (reg >> 2);
        Pk[(long)row * Nout + colb + n * 32] = acc[m][n][reg];
      }
}

// ---------------- bf16 MFMA partial GEMM (h-GEMM), unchanged from R3 ----------------
__global__ __launch_bounds__(256) void gemm_bt(
    const unsigned short* __restrict__ A, const unsigned short* __restrict__ BT,
    const int lda, const int ldbt, const int kLen, const int Nout,
    float* __restrict__ P) {
  __shared__ unsigned short As[128 * 64];
  __shared__ unsigned short Bs[128 * 64];
  const int tid = threadIdx.x;
  const int w = tid >> 6, l = tid & 63;
  const int wr = w >> 1, wc = w & 1;
  const int nwg2d = gridDim.x * gridDim.y;
  const int lin = blockIdx.x + gridDim.x * blockIdx.y;
  const int wg = (lin & 7) * (nwg2d >> 3) + (lin >> 3);
  const int bx = wg % gridDim.x, by = wg / gridDim.x;
  const int aRow0 = by * 128, bRow0 = bx * 128;
  const int kz = blockIdx.z;
  const int lrow8 = l >> 3;
  const int lk8 = (l & 7) * 8;
  f32x4 acc[4][4] = {};
  const int kbeg = kz * kLen, kend = kbeg + kLen;

  for (int k0 = kbeg; k0 < kend; k0 += 64) {
    __syncthreads();
#pragma unroll
    for (int i = 0; i < 4; ++i) {
      const int ch = w * 4 + i;
      gload16(A + (long)(aRow0 + ch * 8 + lrow8) * lda + k0 + lk8, &As[ch * 512]);
      gload16(BT + (long)(bRow0 + ch * 8 + lrow8) * ldbt + k0 + lk8, &Bs[ch * 512]);
    }
    __syncthreads();
#pragma unroll
    for (int ks = 0; ks < 2; ++ks) {
      bf16x8 av[4], bv[4];
#pragma unroll
      for (int m = 0; m < 4; ++m)
        av[m] = *reinterpret_cast<const bf16x8*>(
            &As[(wr * 64 + m * 16 + (l & 15)) * 64 + ks * 32 + (l >> 4) * 8]);
#pragma unroll
      for (int n = 0; n < 4; ++n)
        bv[n] = *reinterpret_cast<const bf16x8*>(
            &Bs[(wc * 64 + n * 16 + (l & 15)) * 64 + ks * 32 + (l >> 4) * 8]);
#pragma unroll
      for (int m = 0; m < 4; ++m)
#pragma unroll
        for (int n = 0; n < 4; ++n)
          acc[m][n] = __builtin_amdgcn_mfma_f32_16x16x32_bf16(av[m], bv[n], acc[m][n], 0, 0, 0);
    }
  }

  float* Pk = P + (long)kz * NN * Nout;
  const int lr = (l >> 4) * 4;
  const int lc = l & 15;
#pragma unroll
  for (int m = 0; m < 4; ++m)
#pragma unroll
    for (int n = 0; n < 4; ++n) {
      const int rowb = aRow0 + wr * 64 + m * 16 + lr;
      const int col = bRow0 + wc * 64 + n * 16 + lc;
#pragma unroll
      for (int j = 0; j < 4; ++j)
        Pk[(long)(rowb + j) * Nout + col] = acc[m][n][j];
    }
}

// ---- reduce1: S64 = sum partials (= 64 * A_norm-ish); Z1 = -dinv*S64/64 ----
// Acomb[512:1024) = bf16(Z1); Z1T = fp8(2048*dinv*Z1)^T (next GEMM's B operand)
__global__ void reduce1_kernel(const float* __restrict__ P, const int nsplit,
                               const float* __restrict__ dinv,
                               unsigned char* __restrict__ Z1T,
                               unsigned short* __restrict__ Acomb) {
  __shared__ float tile[64][65];
  const int c0 = blockIdx.x * 64; // col base (0..511)
  const int r0 = blockIdx.y * 64; // row base (0..8191)
  const int t = threadIdx.x;
#pragma unroll
  for (int it = 0; it < 16; ++it) {
    int e = it * 256 + t;
    int r = e >> 6, c = e & 63;
    long off = (long)(r0 + r) * NF + c0 + c;
    float s = 0.f;
    for (int sp = 0; sp < nsplit; ++sp) s += P[(long)sp * NN * NF + off];
    const float di = dinv[r0 + r];
    const float z = -di * s * 0.015625f; // /64
    tile[r][c] = 2048.f * di * z;        // scaled fp8 operand for next GEMM
    Acomb[(long)(r0 + r) * 1536 + 512 + c0 + c] = f2bf(z);
  }
  __syncthreads();
#pragma unroll
  for (int it = 0; it < 16; ++it) {
    int e = it * 256 + t;
    int rr = e >> 6, cc = e & 63;
    Z1T[(long)(c0 + rr) * NN + r0 + cc] = f2fp8(tile[cc][rr]);
  }
}

// ---- reduce2: Z2 = -2*dinv*(sum partials)/2048 - x; write Acomb[1024:1536) ----
__global__ void reduce2_kernel(const float* __restrict__ P, const int nsplit,
                               const float* __restrict__ x, const float* __restrict__ dinv,
                               unsigned short* __restrict__ Acomb) {
  const long idx4 = (long)blockIdx.x * 256 + threadIdx.x; // float4 idx over 8192*512/4
  const int r = (int)(idx4 >> 7);
  const int c = (int)(idx4 & 127) * 4;
  float4 s = make_float4(0.f, 0.f, 0.f, 0.f);
  for (int sp = 0; sp < nsplit; ++sp) {
    float4 p = reinterpret_cast<const float4*>(P)[(long)sp * (NN * NF / 4) + idx4];
    s.x += p.x; s.y += p.y; s.z += p.z; s.w += p.w;
  }
  const float m2d = -dinv[r] * 0.0009765625f; // -2*dinv/2048
  float4 xv = reinterpret_cast<const float4*>(x)[idx4];
  ushort4 o;
  o.x = f2bf(m2d * s.x - xv.x);
  o.y = f2bf(m2d * s.y - xv.y);
  o.z = f2bf(m2d * s.z - xv.z);
  o.w = f2bf(m2d * s.w - xv.w);
  *reinterpret_cast<ushort4*>(&Acomb[(long)r * 1536 + 1024 + c]) = o;
}

// ---- u: h = relu(sum h-partials + cheb_b); v[i][c] = h . gc2_W[:,c] ----
__global__ void u_kernel(const float* __restrict__ P, const int nsplit,
                         const float* __restrict__ chebb, const float* __restrict__ gw,
                         float* __restrict__ v) {
  const int i = blockIdx.x, t = threadIdx.x;
  float s = chebb[t];
  for (int sp = 0; sp < nsplit; ++sp) s += P[(long)sp * NN * NH + (long)i * NH + t];
  float hv = s > 0.f ? s : 0.f;
  float p0 = hv * gw[t * 2];
  float p1 = hv * gw[t * 2 + 1];
  for (int o = 32; o; o >>= 1) {
    p0 += __shfl_down(p0, o, 64);
    p1 += __shfl_down(p1, o, 64);
  }
  __shared__ float s0[4], s1[4];
  if ((t & 63) == 0) { s0[t >> 6] = p0; s1[t >> 6] = p1; }
  __syncthreads();
  if (t == 0) {
    v[i * 2] = s0[0] + s0[1] + s0[2] + s0[3];
    v[i * 2 + 1] = s1[0] + s1[1] + s1[2] + s1[3];
  }
}

// ---- logits: 8 rows per block (v L2-reuse); logits[i][c] = fp8adj[i,:].v[:,c] + gb[c] ----
__global__ void logits8_kernel(const unsigned char* __restrict__ A8,
                               const float* __restrict__ v,
                               const float* __restrict__ gb, float* __restrict__ logits) {
  const int g = blockIdx.x; // 1024 groups of 8 rows
  const int t = threadIdx.x;
  float a0[8] = {}, a1[8] = {};
#pragma unroll
  for (int it = 0; it < 2; ++it) {
    const int idx = it * 256 + t; // uint4 index within a row (512 per row)
    float4 vs[8];
#pragma unroll
    for (int q2 = 0; q2 < 8; ++q2) vs[q2] = reinterpret_cast<const float4*>(v)[idx * 8 + q2];
#pragma unroll
    for (int r = 0; r < 8; ++r) {
      uint4 pk = reinterpret_cast<const uint4*>(A8 + (long)(g * 8 + r) * NN)[idx];
      unsigned uu[4] = {pk.x, pk.y, pk.z, pk.w};
#pragma unroll
      for (int q = 0; q < 4; ++q) {
#pragma unroll
        for (int b2 = 0; b2 < 2; ++b2) {
          const float f0 = fp8tof((uu[q] >> (b2 * 16)) & 0xFFu);
          const float f1 = fp8tof((uu[q] >> (b2 * 16 + 8)) & 0xFFu);
          const float4 wv = vs[q * 2 + b2];
          a0[r] += f0 * wv.x + f1 * wv.z;
          a1[r] += f0 * wv.y + f1 * wv.w;
        }
      }
    }
  }
  __shared__ float sm0[8][4], sm1[8][4];
#pragma unroll
  for (int r = 0; r < 8; ++r) {
    float x0 = a0[r], x1 = a1[r];
    for (int o = 32; o; o >>= 1) {
      x0 += __shfl_down(x0, o, 64);
      x1 += __shfl_down(x1, o, 64);
    }
    if ((t & 63) == 0) { sm0[r][t >> 6] = x0; sm1[r][t >> 6] = x1; }
  }
  __syncthreads();
  if (t < 8) {
    logits[(g * 8 + t) * 2] = sm0[t][0] + sm0[t][1] + sm0[t][2] + sm0[t][3] + gb[0];
    logits[(g * 8 + t) * 2 + 1] = sm1[t][0] + sm1[t][1] + sm1[t][2] + sm1[t][3] + gb[1];
  }
}

// ---------------- out[c] = max_i logits[i][c] ----------------
__global__ void maxpool_kernel(const float* __restrict__ logits, float* __restrict__ out) {
  const int t = threadIdx.x;
  float m0 = -3.4e38f, m1 = -3.4e38f;
  for (int i = t; i < NN; i += 256) {
    m0 = fmaxf(m0, logits[i * 2]);
    m1 = fmaxf(m1, logits[i * 2 + 1]);
  }
  for (int o = 32; o; o >>= 1) {
    m0 = fmaxf(m0, __shfl_down(m0, o, 64));
    m1 = fmaxf(m1, __shfl_down(m1, o, 64));
  }
  __shared__ float s0[4], s1[4];
  if ((t & 63) == 0) { s0[t >> 6] = m0; s1[t >> 6] = m1; }
  __syncthreads();
  if (t == 0) {
    out[0] = fmaxf(fmaxf(s0[0], s0[1]), fmaxf(s0[2], s0[3]));
    out[1] = fmaxf(fmaxf(s1[0], s1[1]), fmaxf(s1[2], s1[3]));
  }
}

extern "C" void kernel_launch(void* const* d_in, const int* in_sizes, int n_in,
                              void* d_out, int out_size, void* d_ws, size_t ws_size,
                              hipStream_t stream) {
  (void)in_sizes; (void)n_in; (void)out_size;
  const float* x = (const float*)d_in[0];       // [8192,512]
  const float* adj = (const float*)d_in[1];     // [8192,8192]
  const float* cheb_W = (const float*)d_in[2];  // [3,512,256] = [1536,256]
  const float* cheb_b = (const float*)d_in[3];  // [256]
  const float* gc2_W = (const float*)d_in[4];   // [256,2]
  const float* gc2_b = (const float*)d_in[5];   // [2]
  float* out = (float*)d_out;                   // [2]

  char* ws = (char*)d_ws;
  unsigned char* A8     = (unsigned char*)(ws);                // 64 MiB fp8 adj, live to end
  unsigned char* BTbuf  = (unsigned char*)(ws + 67108864L);    // 4 MiB fp8: yT then Z1T
  unsigned short* Acomb = (unsigned short*)(ws + 71303168L);   // 24 MiB [x|Z1|Z2] bf16
  unsigned short* WcT   = (unsigned short*)(ws + 96468992L);   // 768 KiB (dead after hGEMM)
  float* v              = (float*)(ws + 96468992L);            // 64 KiB, overlays WcT
  float* logits         = (float*)(ws + 96534528L);            // 64 KiB, overlays WcT
  float* P              = (float*)(ws + 97255424L);            // split-K partials

  const long PBASE = 97255424L;
  int ks = 1;
  if (ws_size >= (size_t)(PBASE + 4L * 16777216L + 65536L)) ks = 4;
  else if (ws_size >= (size_t)(PBASE + 2L * 16777216L + 65536L)) ks = 2;
  const int hks = ks; // h-GEMM split (P use: hks*8 MiB <= ks*16 MiB)
  const long pbytes = (long)ks * 16777216L;
  float* dinv = (float*)(ws + PBASE + pbytes);

  // fused fp8 cast of adj + row-degree -> dinv
  castadj_deg_kernel<<<dim3(NN), dim3(256), 0, stream>>>(adj, A8, dinv);
  // yT = fp8(64*dinv .* x)^T; Acomb[0:512) = bf16(x)
  castx_kernel<<<dim3(8, 128), dim3(256), 0, stream>>>(x, dinv, BTbuf, Acomb);
  castw_kernel<<<dim3(4, 24), dim3(256), 0, stream>>>(cheb_W, WcT);
  // P = split-K partials of A8 @ y   (= 64 * adj @ (dinv.*x))
  gemm_fp8<<<dim3(4, 64, ks), dim3(256), 0, stream>>>(A8, BTbuf, NN, NN, NN / ks, NF, P);
  // Z1 = -dinv.*(sum P)/64 -> Z1T fp8 (scaled 2048*dinv) + Acomb[512:1024)
  reduce1_kernel<<<dim3(8, 128), dim3(256), 0, stream>>>(P, ks, dinv, BTbuf, Acomb);
  // P = split-K partials of A8 @ (2048*dinv.*Z1)
  gemm_fp8<<<dim3(4, 64, ks), dim3(256), 0, stream>>>(A8, BTbuf, NN, NN, NN / ks, NF, P);
  // Z2 = -2*dinv.*(sum P)/2048 - x -> Acomb[1024:1536)
  reduce2_kernel<<<dim3(4096), dim3(256), 0, stream>>>(P, ks, x, dinv, Acomb);
  // P = split-K partials of [x|Z1|Z2] @ [W0;W1;W2]  (bf16)
  gemm_bt<<<dim3(2, 64, hks), dim3(256), 0, stream>>>(Acomb, WcT, 1536, 1536, 1536 / hks, NH, P);
  // h = relu(sum P + cheb_b); v = h @ gc2_W
  u_kernel<<<dim3(NN), dim3(256), 0, stream>>>(P, hks, cheb_b, gc2_W, v);
  // logits = fp8(adj) @ v + b, 8 rows/block for v reuse
  logits8_kernel<<<dim3(1024), dim3(256), 0, stream>>>(A8, v, gc2_b, logits);
  maxpool_kernel<<<dim3(1), dim3(256), 0, stream>>>(logits, out);
}

// Round 5
// 366.799 us; speedup vs baseline: 1.1043x; 1.1043x over previous
//
#include <hip/hip_runtime.h>
#include <stdint.h>

#define NN 8192
#define NF 512
#define NH 256

typedef __bf16 bf16_t;
typedef bf16_t bf16x8 __attribute__((ext_vector_type(8)));
typedef float f32x4 __attribute__((ext_vector_type(4)));

// round-to-nearest-even f32 -> bf16 bit pattern
__device__ __forceinline__ unsigned short f2bf(float f) {
  union { float f; unsigned u; } v; v.f = f;
  unsigned r = v.u + 0x7FFFu + ((v.u >> 16) & 1u);
  return (unsigned short)(r >> 16);
}

__device__ __forceinline__ float bf2f(unsigned short u) {
  union { unsigned u; float f; } v; v.u = (unsigned)u << 16;
  return v.f;
}

// async global->LDS, 16B per lane; LDS dest is wave-uniform base + lane*16
__device__ __forceinline__ void gload16(const void* g, void* l) {
  __builtin_amdgcn_global_load_lds(
      (__attribute__((address_space(1))) void*)g,
      (__attribute__((address_space(3))) void*)l, 16, 0, 0);
}

// ---- fused: Abf = bf16(adj) raw cast AND dinv = rsqrt(max(rowsum,1e-12)) ----
__global__ void castadj_deg_kernel(const float* __restrict__ adj,
                                   unsigned short* __restrict__ Abf,
                                   float* __restrict__ dinv) {
  const int i = blockIdx.x, t = threadIdx.x;
  const float4* row = reinterpret_cast<const float4*>(adj + (long)i * NN);
  ushort4* orow = reinterpret_cast<ushort4*>(Abf + (long)i * NN);
  float s = 0.f;
#pragma unroll
  for (int it = 0; it < 8; ++it) {
    float4 a = row[it * 256 + t];
    s += a.x + a.y + a.z + a.w;
    ushort4 o;
    o.x = f2bf(a.x); o.y = f2bf(a.y); o.z = f2bf(a.z); o.w = f2bf(a.w);
    orow[it * 256 + t] = o;
  }
  for (int o = 32; o; o >>= 1) s += __shfl_down(s, o, 64);
  __shared__ float sm[4];
  if ((t & 63) == 0) sm[t >> 6] = s;
  __syncthreads();
  if (t == 0) {
    float d = fmaxf(sm[0] + sm[1] + sm[2] + sm[3], 1e-12f);
    dinv[i] = rsqrtf(d);
  }
}

// ---- xbf = bf16(x), row-major [8192][512] ----
__global__ void castxbf_kernel(const float* __restrict__ x, unsigned short* __restrict__ xbf) {
  const long idx4 = (long)blockIdx.x * 256 + threadIdx.x; // 1,048,576 float4s
  float4 a = reinterpret_cast<const float4*>(x)[idx4];
  ushort4 o;
  o.x = f2bf(a.x); o.y = f2bf(a.y); o.z = f2bf(a.z); o.w = f2bf(a.w);
  reinterpret_cast<ushort4*>(xbf)[idx4] = o;
}

// ---- WTc[c][k] bf16, c in [0,768): c<256 -> W0-W2; [256,512) -> W1; [512,768) -> W2 ----
__global__ void buildwt_kernel(const float* __restrict__ W, unsigned short* __restrict__ WTc) {
  const int idx = blockIdx.x * 256 + threadIdx.x; // 393216
  const int c = idx >> 9, k = idx & 511;
  float val;
  if (c < 256) val = W[k * 256 + c] - W[262144 + k * 256 + c];
  else if (c < 512) val = W[131072 + k * 256 + (c - 256)];
  else val = W[262144 + k * 256 + (c - 512)];
  WTc[(long)c * 512 + k] = f2bf(val);
}

// ---------------- bf16 MFMA GEMM (m97-style 128x128 tile, BK=64, 4 waves) ----------------
// B given as BT [N][K]. XCD-aware bijective swizzle (nwg2d % 8 == 0 for all our grids).
// MODE 0: write bf16 partials Pb[kz][M][Nout]
// MODE 1 (gemm_w): col<256 -> Q0[row][col] f32; col>=256 -> q12T[col-256][row] = bf16(dinv[row]*v)
template <int MODE>
__global__ __launch_bounds__(256) void gemm_bt(
    const unsigned short* __restrict__ A, const unsigned short* __restrict__ BT,
    const int lda, const int ldbt, const int kLen, const int Nout,
    unsigned short* __restrict__ Pb, float* __restrict__ Q0,
    unsigned short* __restrict__ q12T, const float* __restrict__ dinv) {
  __shared__ unsigned short As[128 * 64];
  __shared__ unsigned short Bs[128 * 64];
  const int tid = threadIdx.x;
  const int w = tid >> 6, l = tid & 63;
  const int wr = w >> 1, wc = w & 1;
  const int nwg2d = gridDim.x * gridDim.y;
  const int lin = blockIdx.x + gridDim.x * blockIdx.y;
  const int wg = (lin & 7) * (nwg2d >> 3) + (lin >> 3);
  const int bx = wg % gridDim.x, by = wg / gridDim.x;
  const int aRow0 = by * 128, bRow0 = bx * 128;
  const int kz = blockIdx.z;
  const int lrow8 = l >> 3;
  const int lk8 = (l & 7) * 8;
  f32x4 acc[4][4] = {};
  const int kbeg = kz * kLen, kend = kbeg + kLen;

  for (int k0 = kbeg; k0 < kend; k0 += 64) {
    __syncthreads();
#pragma unroll
    for (int i = 0; i < 4; ++i) {
      const int ch = w * 4 + i; // chunk 0..15, 8 rows x 64 k each (1024B)
      gload16(A + (long)(aRow0 + ch * 8 + lrow8) * lda + k0 + lk8, &As[ch * 512]);
      gload16(BT + (long)(bRow0 + ch * 8 + lrow8) * ldbt + k0 + lk8, &Bs[ch * 512]);
    }
    __syncthreads(); // vmcnt(0) drained before s_barrier -> LDS valid
#pragma unroll
    for (int ks = 0; ks < 2; ++ks) {
      bf16x8 av[4], bv[4];
#pragma unroll
      for (int m = 0; m < 4; ++m)
        av[m] = *reinterpret_cast<const bf16x8*>(
            &As[(wr * 64 + m * 16 + (l & 15)) * 64 + ks * 32 + (l >> 4) * 8]);
#pragma unroll
      for (int n = 0; n < 4; ++n)
        bv[n] = *reinterpret_cast<const bf16x8*>(
            &Bs[(wc * 64 + n * 16 + (l & 15)) * 64 + ks * 32 + (l >> 4) * 8]);
#pragma unroll
      for (int m = 0; m < 4; ++m)
#pragma unroll
        for (int n = 0; n < 4; ++n)
          acc[m][n] = __builtin_amdgcn_mfma_f32_16x16x32_bf16(av[m], bv[n], acc[m][n], 0, 0, 0);
    }
  }

  // C elem (row = base + (l>>4)*4 + j, col = base + (l&15))  [m89-verified]
  const int lr = (l >> 4) * 4;
  const int lc = l & 15;
#pragma unroll
  for (int m = 0; m < 4; ++m)
#pragma unroll
    for (int n = 0; n < 4; ++n) {
      const int rowb = aRow0 + wr * 64 + m * 16 + lr;
      const int col = bRow0 + wc * 64 + n * 16 + lc;
      if (MODE == 0) {
        unsigned short* Pk = Pb + (long)kz * NN * Nout;
#pragma unroll
        for (int j = 0; j < 4; ++j)
          Pk[(long)(rowb + j) * Nout + col] = f2bf(acc[m][n][j]);
      } else {
        if (col < 256) {
#pragma unroll
          for (int j = 0; j < 4; ++j)
            Q0[(long)(rowb + j) * 256 + col] = acc[m][n][j];
        } else {
          unsigned short pv[4];
#pragma unroll
          for (int j = 0; j < 4; ++j) pv[j] = f2bf(dinv[rowb + j] * acc[m][n][j]);
          *reinterpret_cast<ushort4*>(&q12T[(long)(col - 256) * NN + rowb]) =
              *reinterpret_cast<ushort4*>(pv);
        }
      }
    }
}

// ---- reduceA: S = sum_z Pb[z] (= adj_bf @ (dinv.*[q1|q2])) over [8192][512] ----
// c<256: s1[r][c] = dinv[r]*S (f32).  c>=256: bT2[c-256][r] = bf16(dinv[r]^2 * S) (transposed)
__global__ void reduceA_kernel(const unsigned short* __restrict__ Pb, const int ks,
                               const float* __restrict__ dinv,
                               float* __restrict__ s1, unsigned short* __restrict__ bT2) {
  __shared__ float tile[64][65];
  const int c0 = blockIdx.x * 64; // [0,512)
  const int r0 = blockIdx.y * 64;
  const int t = threadIdx.x;
  if (c0 < 256) {
#pragma unroll
    for (int it = 0; it < 16; ++it) {
      int e = it * 256 + t;
      int r = e >> 6, c = e & 63;
      long off = (long)(r0 + r) * 512 + c0 + c;
      float S = 0.f;
      for (int z = 0; z < ks; ++z) S += bf2f(Pb[(long)z * NN * 512 + off]);
      s1[(long)(r0 + r) * 256 + c0 + c] = dinv[r0 + r] * S;
    }
  } else {
#pragma unroll
    for (int it = 0; it < 16; ++it) {
      int e = it * 256 + t;
      int r = e >> 6, c = e & 63;
      long off = (long)(r0 + r) * 512 + c0 + c;
      float S = 0.f;
      for (int z = 0; z < ks; ++z) S += bf2f(Pb[(long)z * NN * 512 + off]);
      const float di = dinv[r0 + r];
      tile[r][c] = di * di * S;
    }
    __syncthreads();
#pragma unroll
    for (int it = 0; it < 16; ++it) {
      int e = it * 256 + t;
      int rr = e >> 6, cc = e & 63;
      bT2[(long)(c0 - 256 + rr) * NN + r0 + cc] = f2bf(tile[cc][rr]);
    }
  }
}

// ---- combine: h = relu(q0 - s1 + 2*dinv[i]*sum_z P_B[z] + cheb_b); v = h @ gc2_W ----
__global__ void combine_u_kernel(const float* __restrict__ Q0, const float* __restrict__ s1,
                                 const unsigned short* __restrict__ Pb, const int ks,
                                 const float* __restrict__ dinv, const float* __restrict__ chebb,
                                 const float* __restrict__ gw, float* __restrict__ v) {
  const int i = blockIdx.x, t = threadIdx.x; // t = hidden channel
  float S = 0.f;
  for (int z = 0; z < ks; ++z) S += bf2f(Pb[(long)z * NN * 256 + (long)i * 256 + t]);
  float hv = Q0[(long)i * 256 + t] - s1[(long)i * 256 + t] + 2.f * dinv[i] * S + chebb[t];
  hv = hv > 0.f ? hv : 0.f;
  float p0 = hv * gw[t * 2];
  float p1 = hv * gw[t * 2 + 1];
  for (int o = 32; o; o >>= 1) {
    p0 += __shfl_down(p0, o, 64);
    p1 += __shfl_down(p1, o, 64);
  }
  __shared__ float s0[4], s1s[4];
  if ((t & 63) == 0) { s0[t >> 6] = p0; s1s[t >> 6] = p1; }
  __syncthreads();
  if (t == 0) {
    v[i * 2] = s0[0] + s0[1] + s0[2] + s0[3];
    v[i * 2 + 1] = s1s[0] + s1s[1] + s1s[2] + s1s[3];
  }
}

// ---- logits: 8 rows per block; logits[i][c] = Abf[i,:] . v[:,c] + gb[c] ----
__global__ void logits8_kernel(const unsigned short* __restrict__ Abf,
                               const float* __restrict__ v,
                               const float* __restrict__ gb, float* __restrict__ logits) {
  const int g = blockIdx.x; // 1024 groups of 8 rows
  const int t = threadIdx.x;
  const float4* vv = reinterpret_cast<const float4*>(v);
  float a0[8] = {}, a1[8] = {};
#pragma unroll
  for (int it = 0; it < 4; ++it) {
    const int idx = it * 256 + t; // uint4 index within a row (1024 per row, 8 bf16 each)
    float4 vs[4];
#pragma unroll
    for (int q = 0; q < 4; ++q) vs[q] = vv[idx * 4 + q]; // {v[j][0],v[j][1],v[j+1][0],v[j+1][1]}
#pragma unroll
    for (int r = 0; r < 8; ++r) {
      uint4 pk = reinterpret_cast<const uint4*>(Abf + (long)(g * 8 + r) * NN)[idx];
      unsigned uu[4] = {pk.x, pk.y, pk.z, pk.w};
#pragma unroll
      for (int q = 0; q < 4; ++q) {
        union { unsigned u; float f; } flo, fhi;
        flo.u = uu[q] << 16;
        fhi.u = uu[q] & 0xFFFF0000u;
        a0[r] += flo.f * vs[q].x + fhi.f * vs[q].z;
        a1[r] += flo.f * vs[q].y + fhi.f * vs[q].w;
      }
    }
  }
  __shared__ float sm0[8][4], sm1[8][4];
#pragma unroll
  for (int r = 0; r < 8; ++r) {
    float x0 = a0[r], x1 = a1[r];
    for (int o = 32; o; o >>= 1) {
      x0 += __shfl_down(x0, o, 64);
      x1 += __shfl_down(x1, o, 64);
    }
    if ((t & 63) == 0) { sm0[r][t >> 6] = x0; sm1[r][t >> 6] = x1; }
  }
  __syncthreads();
  if (t < 8) {
    logits[(g * 8 + t) * 2] = sm0[t][0] + sm0[t][1] + sm0[t][2] + sm0[t][3] + gb[0];
    logits[(g * 8 + t) * 2 + 1] = sm1[t][0] + sm1[t][1] + sm1[t][2] + sm1[t][3] + gb[1];
  }
}

// ---------------- out[c] = max_i logits[i][c] ----------------
__global__ void maxpool_kernel(const float* __restrict__ logits, float* __restrict__ out) {
  const int t = threadIdx.x;
  float m0 = -3.4e38f, m1 = -3.4e38f;
  for (int i = t; i < NN; i += 256) {
    m0 = fmaxf(m0, logits[i * 2]);
    m1 = fmaxf(m1, logits[i * 2 + 1]);
  }
  for (int o = 32; o; o >>= 1) {
    m0 = fmaxf(m0, __shfl_down(m0, o, 64));
    m1 = fmaxf(m1, __shfl_down(m1, o, 64));
  }
  __shared__ float s0[4], s1[4];
  if ((t & 63) == 0) { s0[t >> 6] = m0; s1[t >> 6] = m1; }
  __syncthreads();
  if (t == 0) {
    out[0] = fmaxf(fmaxf(s0[0], s0[1]), fmaxf(s0[2], s0[3]));
    out[1] = fmaxf(fmaxf(s1[0], s1[1]), fmaxf(s1[2], s1[3]));
  }
}

extern "C" void kernel_launch(void* const* d_in, const int* in_sizes, int n_in,
                              void* d_out, int out_size, void* d_ws, size_t ws_size,
                              hipStream_t stream) {
  (void)in_sizes; (void)n_in; (void)out_size;
  const float* x = (const float*)d_in[0];       // [8192,512]
  const float* adj = (const float*)d_in[1];     // [8192,8192]
  const float* cheb_W = (const float*)d_in[2];  // [3,512,256]
  const float* cheb_b = (const float*)d_in[3];  // [256]
  const float* gc2_W = (const float*)d_in[4];   // [256,2]
  const float* gc2_b = (const float*)d_in[5];   // [2]
  float* out = (float*)d_out;                   // [2]

  char* ws = (char*)d_ws;
  unsigned short* Abf  = (unsigned short*)(ws);               // 128 MiB bf16 adj, live to end
  unsigned short* xbf  = (unsigned short*)(ws + 134217728L);  // 8 MiB
  unsigned short* WTc  = (unsigned short*)(ws + 142606336L);  // 768 KiB [768][512]
  float* Q0            = (float*)(ws + 143392768L);           // 8 MiB f32 [8192][256] = x(W0-W2)
  unsigned short* q12T = (unsigned short*)(ws + 151781376L);  // 8 MiB bf16 [512][8192]
  float* s1            = (float*)(ws + 160169984L);           // 8 MiB f32 [8192][256]
  unsigned short* bT2  = (unsigned short*)(ws + 168558592L);  // 4 MiB bf16 [256][8192]
  float* dinv          = (float*)(ws + 172752896L);           // 32 KiB
  float* v             = (float*)(ws + 172785664L);           // 64 KiB
  float* logits        = (float*)(ws + 172851200L);           // 64 KiB
  unsigned short* P    = (unsigned short*)(ws + 172916736L);  // bf16 split-K partials

  const long PBASE = 172916736L;
  int ks = 1;
  if (ws_size >= (size_t)(PBASE + 4L * 8388608L)) ks = 4;
  else if (ws_size >= (size_t)(PBASE + 2L * 8388608L)) ks = 2;

  // 1) Abf = bf16(adj); dinv = rsqrt(rowsum)
  castadj_deg_kernel<<<dim3(NN), dim3(256), 0, stream>>>(adj, Abf, dinv);
  // 2) xbf = bf16(x); WTc = [W0-W2|W1|W2]^T bf16
  castxbf_kernel<<<dim3(4096), dim3(256), 0, stream>>>(x, xbf);
  buildwt_kernel<<<dim3(1536), dim3(256), 0, stream>>>(cheb_W, WTc);
  // 3) gemm_w: Q = xbf @ Wcat; epilogue -> Q0 (f32, cols<256), q12T = (dinv.*[q1|q2])^T bf16
  gemm_bt<1><<<dim3(6, 64, 1), dim3(256), 0, stream>>>(xbf, WTc, 512, 512, 512, 768,
      (unsigned short*)nullptr, Q0, q12T, dinv);
  // 4) GEMM_A: P = split-K bf16 partials of Abf @ (dinv.*[q1|q2])   [8192][512]
  gemm_bt<0><<<dim3(4, 64, ks), dim3(256), 0, stream>>>(Abf, q12T, NN, NN, NN / ks, 512,
      P, (float*)nullptr, (unsigned short*)nullptr, (const float*)nullptr);
  // 5) reduceA: s1 = dinv.*S[:,0:256] f32; bT2 = (dinv^2 .* S[:,256:512])^T bf16
  reduceA_kernel<<<dim3(8, 128), dim3(256), 0, stream>>>(P, ks, dinv, s1, bT2);
  // 6) GEMM_B: P = split-K bf16 partials of Abf @ (dinv.*s2)   [8192][256]
  gemm_bt<0><<<dim3(2, 64, ks), dim3(256), 0, stream>>>(Abf, bT2, NN, NN, NN / ks, 256,
      P, (float*)nullptr, (unsigned short*)nullptr, (const float*)nullptr);
  // 7) h = relu(Q0 - s1 + 2*dinv.*sumP + b); v = h @ gc2_W
  combine_u_kernel<<<dim3(NN), dim3(256), 0, stream>>>(Q0, s1, P, ks, dinv, cheb_b, gc2_W, v);
  // 8) logits = bf16(adj) @ v + b
  logits8_kernel<<<dim3(1024), dim3(256), 0, stream>>>(Abf, v, gc2_b, logits);
  maxpool_kernel<<<dim3(1), dim3(256), 0, stream>>>(logits, out);
}

// Round 6
// 340.919 us; speedup vs baseline: 1.1881x; 1.0759x over previous
//
#include <hip/hip_runtime.h>
#include <stdint.h>

#define NN 8192
#define NF 512
#define NH 256

typedef __bf16 bf16_t;
typedef bf16_t bf16x8 __attribute__((ext_vector_type(8)));
typedef float f32x4 __attribute__((ext_vector_type(4)));

// round-to-nearest-even f32 -> bf16 bit pattern
__device__ __forceinline__ unsigned short f2bf(float f) {
  union { float f; unsigned u; } v; v.f = f;
  unsigned r = v.u + 0x7FFFu + ((v.u >> 16) & 1u);
  return (unsigned short)(r >> 16);
}

__device__ __forceinline__ float bf2f(unsigned short u) {
  union { unsigned u; float f; } v; v.u = (unsigned)u << 16;
  return v.f;
}

// async global->LDS, 16B per lane; LDS dest is wave-uniform base + lane*16
__device__ __forceinline__ void gload16(const void* g, void* l) {
  __builtin_amdgcn_global_load_lds(
      (__attribute__((address_space(1))) void*)g,
      (__attribute__((address_space(3))) void*)l, 16, 0, 0);
}

// ---- fused: Abf = bf16(adj) raw cast AND dinv = rsqrt(max(rowsum,1e-12)) ----
__global__ void castadj_deg_kernel(const float* __restrict__ adj,
                                   unsigned short* __restrict__ Abf,
                                   float* __restrict__ dinv) {
  const int i = blockIdx.x, t = threadIdx.x;
  const float4* row = reinterpret_cast<const float4*>(adj + (long)i * NN);
  ushort4* orow = reinterpret_cast<ushort4*>(Abf + (long)i * NN);
  float s = 0.f;
#pragma unroll
  for (int it = 0; it < 8; ++it) {
    float4 a = row[it * 256 + t];
    s += a.x + a.y + a.z + a.w;
    ushort4 o;
    o.x = f2bf(a.x); o.y = f2bf(a.y); o.z = f2bf(a.z); o.w = f2bf(a.w);
    orow[it * 256 + t] = o;
  }
  for (int o = 32; o; o >>= 1) s += __shfl_down(s, o, 64);
  __shared__ float sm[4];
  if ((t & 63) == 0) sm[t >> 6] = s;
  __syncthreads();
  if (t == 0) {
    float d = fmaxf(sm[0] + sm[1] + sm[2] + sm[3], 1e-12f);
    dinv[i] = rsqrtf(d);
  }
}

// ---- xbf = bf16(x), row-major [8192][512] ----
__global__ void castxbf_kernel(const float* __restrict__ x, unsigned short* __restrict__ xbf) {
  const long idx4 = (long)blockIdx.x * 256 + threadIdx.x;
  float4 a = reinterpret_cast<const float4*>(x)[idx4];
  ushort4 o;
  o.x = f2bf(a.x); o.y = f2bf(a.y); o.z = f2bf(a.z); o.w = f2bf(a.w);
  reinterpret_cast<ushort4*>(xbf)[idx4] = o;
}

// ---- WTc[c][k] bf16, c in [0,768): c<256 -> W0-W2; [256,512) -> W1; [512,768) -> W2 ----
__global__ void buildwt_kernel(const float* __restrict__ W, unsigned short* __restrict__ WTc) {
  const int idx = blockIdx.x * 256 + threadIdx.x; // 393216
  const int c = idx >> 9, k = idx & 511;
  float val;
  if (c < 256) val = W[k * 256 + c] - W[262144 + k * 256 + c];
  else if (c < 512) val = W[131072 + k * 256 + (c - 256)];
  else val = W[262144 + k * 256 + (c - 512)];
  WTc[(long)c * 512 + k] = f2bf(val);
}

// ================= 8-phase 256x256 bf16 GEMM (T2+T3+T4+T5), bf16 partial out =================
// A [M][NN] bf16 row-major; BT [Nout][NN] bf16 (B transposed). C partial = A[:,kz-range]@B.
// 512 thr = 8 waves (2 Mrow x 4 Ncol), wave owns 128x64 = 8x4 frags 16x16, acc 128 VGPR.
// LDS: per matrix 2 dbuf x 2 k-half x (256 rows x 32 k) = 64 KiB; total 128 KiB, 1 blk/CU.
// Schedule per K-tile t (4 phases, ks=k-half, mh=m-quadrant):
//  p0(ks0,mh0): read av(mh0,kh0)+bv(kh0); stage A[d^1][1]<-t+1.kh1 | p1(ks0,mh1): av; stage B[d^1][1]
//  p2(ks1,mh0): av+bv(kh1);               stage A[d][0] <-t+2.kh0 | p3(ks1,mh1): av; stage B[d][0]
// Each phase: reads; stage; s_barrier; lgkmcnt(0); setprio(1); 16 MFMA; setprio(0); s_barrier.
// vmcnt(4) before p3's closing barrier confirms ALL of tile t+1 (its newest stage is 4 loads old);
// per-wave vmcnt + barrier => all waves' slices landed. Slot overwrites (p2/p3) target slots whose
// last reads completed at p1's lgkmcnt(0)+barrier. Raw s_barrier (no vmcnt drain), rule#18 pins.
// LDS swizzle: byte kb ^= ((r>>1)&3)<<4 within each 64B row (read side); stage pre-swizzles the
// GLOBAL source and keeps LDS dest linear (rule #21).
__device__ __forceinline__ bf16x8 ldfrag(const unsigned short* h, int r, int l) {
  const int kb = ((l >> 4) * 16) ^ (((r >> 1) & 3) << 4);
  return *reinterpret_cast<const bf16x8*>((const char*)h + r * 64 + kb);
}

__device__ __forceinline__ void stage_half(const unsigned short* __restrict__ G,
                                           int gR0, long kByte, unsigned short* lbase,
                                           int w, int tid) {
  const int rr = tid >> 2;                 // dest row 0..127 (call 0) / +128 (call 1)
  const int kb = (tid & 3) * 16;           // dest byte col within 64B row
  const int sw = ((rr >> 1) & 3) << 4;     // same for rr+128
  gload16((const char*)(G + (long)(gR0 + rr) * NN) + kByte + (kb ^ sw),
          (char*)lbase + w * 1024);
  gload16((const char*)(G + (long)(gR0 + 128 + rr) * NN) + kByte + (kb ^ sw),
          (char*)lbase + 8192 + w * 1024);
}

#define BAR() __builtin_amdgcn_s_barrier()
#define SCHED0() __builtin_amdgcn_sched_barrier(0)
#define LGKM0() do { asm volatile("s_waitcnt lgkmcnt(0)" ::: "memory"); SCHED0(); } while (0)

__global__ __launch_bounds__(512) void gemm8(
    const unsigned short* __restrict__ A, const unsigned short* __restrict__ BT,
    const int kLen, const int Nout, unsigned short* __restrict__ Pb) {
  __shared__ unsigned short As[2][2][256 * 32];
  __shared__ unsigned short Bs[2][2][256 * 32];
  const int tid = threadIdx.x;
  const int w = tid >> 6, l = tid & 63;
  const int wr = w >> 2, wc = w & 3;
  // XCD-aware chunked swizzle (nwg2d % 8 == 0 for our grids)
  const int nwg2d = gridDim.x * gridDim.y;
  const int lin = blockIdx.x + gridDim.x * blockIdx.y;
  const int wg = (lin & 7) * (nwg2d >> 3) + (lin >> 3);
  const int bx = wg % gridDim.x, by = wg / gridDim.x;
  const int aRow0 = by * 256, bRow0 = bx * 256;
  const long kbegB = (long)blockIdx.z * kLen * 2; // byte offset along K
  const int nt = kLen >> 6;
  f32x4 acc[8][4] = {};

  // prologue: t0.kh0(A,B), t0.kh1(A,B), t1.kh0(A,B) = 12 loads/wave
  stage_half(A, aRow0, kbegB, &As[0][0][0], w, tid);
  stage_half(BT, bRow0, kbegB, &Bs[0][0][0], w, tid);
  stage_half(A, aRow0, kbegB + 64, &As[0][1][0], w, tid);
  stage_half(BT, bRow0, kbegB + 64, &Bs[0][1][0], w, tid);
  {
    const int t1 = (nt > 1) ? 1 : 0;
    stage_half(A, aRow0, kbegB + (long)t1 * 128, &As[1][0][0], w, tid);
    stage_half(BT, bRow0, kbegB + (long)t1 * 128, &Bs[1][0][0], w, tid);
  }
  asm volatile("s_waitcnt vmcnt(4)" ::: "memory"); // tile0 fully landed (own stake)
  SCHED0();
  BAR(); SCHED0();                                 // all waves' stakes -> tile0 valid

  bf16x8 av[4], bv[4];
  const int la = l & 15;
  for (int t = 0; t < nt; ++t) {
    const int d = t & 1;
    const unsigned short* Ah0 = &As[d][0][0];
    const unsigned short* Ah1 = &As[d][1][0];
    const unsigned short* Bh0 = &Bs[d][0][0];
    const unsigned short* Bh1 = &Bs[d][1][0];
    const int tt1 = (t + 1 < nt) ? t + 1 : nt - 1; // clamped (keeps vmcnt counts exact)
    const int tt2 = (t + 2 < nt) ? t + 2 : nt - 1;

    // ---- phase 0: ks=0, mh=0 ----
#pragma unroll
    for (int m = 0; m < 4; ++m) av[m] = ldfrag(Ah0, wr * 128 + m * 16 + la, l);
#pragma unroll
    for (int n = 0; n < 4; ++n) bv[n] = ldfrag(Bh0, wc * 64 + n * 16 + la, l);
    stage_half(A, aRow0, kbegB + (long)tt1 * 128 + 64, &As[d ^ 1][1][0], w, tid);
    BAR();
    LGKM0();
    __builtin_amdgcn_s_setprio(1);
#pragma unroll
    for (int m = 0; m < 4; ++m)
#pragma unroll
      for (int n = 0; n < 4; ++n)
        acc[m][n] = __builtin_amdgcn_mfma_f32_16x16x32_bf16(av[m], bv[n], acc[m][n], 0, 0, 0);
    __builtin_amdgcn_s_setprio(0);
    BAR(); SCHED0();

    // ---- phase 1: ks=0, mh=1 (reuse bv) ----
#pragma unroll
    for (int m = 0; m < 4; ++m) av[m] = ldfrag(Ah0, wr * 128 + 64 + m * 16 + la, l);
    stage_half(BT, bRow0, kbegB + (long)tt1 * 128 + 64, &Bs[d ^ 1][1][0], w, tid);
    BAR();
    LGKM0();
    __builtin_amdgcn_s_setprio(1);
#pragma unroll
    for (int m = 0; m < 4; ++m)
#pragma unroll
      for (int n = 0; n < 4; ++n)
        acc[4 + m][n] = __builtin_amdgcn_mfma_f32_16x16x32_bf16(av[m], bv[n], acc[4 + m][n], 0, 0, 0);
    __builtin_amdgcn_s_setprio(0);
    BAR(); SCHED0();

    // ---- phase 2: ks=1, mh=0 ----
#pragma unroll
    for (int m = 0; m < 4; ++m) av[m] = ldfrag(Ah1, wr * 128 + m * 16 + la, l);
#pragma unroll
    for (int n = 0; n < 4; ++n) bv[n] = ldfrag(Bh1, wc * 64 + n * 16 + la, l);
    stage_half(A, aRow0, kbegB + (long)tt2 * 128, &As[d][0][0], w, tid);
    BAR();
    LGKM0();
    __builtin_amdgcn_s_setprio(1);
#pragma unroll
    for (int m = 0; m < 4; ++m)
#pragma unroll
      for (int n = 0; n < 4; ++n)
        acc[m][n] = __builtin_amdgcn_mfma_f32_16x16x32_bf16(av[m], bv[n], acc[m][n], 0, 0, 0);
    __builtin_amdgcn_s_setprio(0);
    BAR(); SCHED0();

    // ---- phase 3: ks=1, mh=1 ----
#pragma unroll
    for (int m = 0; m < 4; ++m) av[m] = ldfrag(Ah1, wr * 128 + 64 + m * 16 + la, l);
    stage_half(BT, bRow0, kbegB + (long)tt2 * 128, &Bs[d][0][0], w, tid);
    BAR();
    LGKM0();
    __builtin_amdgcn_s_setprio(1);
#pragma unroll
    for (int m = 0; m < 4; ++m)
#pragma unroll
      for (int n = 0; n < 4; ++n)
        acc[4 + m][n] = __builtin_amdgcn_mfma_f32_16x16x32_bf16(av[m], bv[n], acc[4 + m][n], 0, 0, 0);
    __builtin_amdgcn_s_setprio(0);
    asm volatile("s_waitcnt vmcnt(4)" ::: "memory"); // tile t+1 fully landed (own stake)
    SCHED0();
    BAR(); SCHED0();                                 // all waves -> t+1 valid
  }

  // C elem (row = base + (l>>4)*4 + j, col = base + (l&15))  [m89-verified]
  unsigned short* Pk = Pb + (long)blockIdx.z * NN * Nout;
  const int lr = (l >> 4) * 4;
#pragma unroll
  for (int m = 0; m < 8; ++m)
#pragma unroll
    for (int n = 0; n < 4; ++n) {
      const int rowb = aRow0 + wr * 128 + m * 16 + lr;
      const int col = bRow0 + wc * 64 + n * 16 + la;
#pragma unroll
      for (int j = 0; j < 4; ++j)
        Pk[(long)(rowb + j) * Nout + col] = f2bf(acc[m][n][j]);
    }
}

// ---------------- m97-style 128x128 bf16 GEMM, used only for the small W-projection ----------------
// MODE 1 epilogue: col<256 -> Q0[row][col] f32; col>=256 -> q12T[col-256][row] = bf16(dinv[row]*v)
__global__ __launch_bounds__(256) void gemm_w(
    const unsigned short* __restrict__ A, const unsigned short* __restrict__ BT,
    const int lda, const int ldbt, const int kLen, const int Nout,
    float* __restrict__ Q0, unsigned short* __restrict__ q12T,
    const float* __restrict__ dinv) {
  __shared__ unsigned short As[128 * 64];
  __shared__ unsigned short Bs[128 * 64];
  const int tid = threadIdx.x;
  const int w = tid >> 6, l = tid & 63;
  const int wr = w >> 1, wc = w & 1;
  const int nwg2d = gridDim.x * gridDim.y;
  const int lin = blockIdx.x + gridDim.x * blockIdx.y;
  const int wg = (lin & 7) * (nwg2d >> 3) + (lin >> 3);
  const int bx = wg % gridDim.x, by = wg / gridDim.x;
  const int aRow0 = by * 128, bRow0 = bx * 128;
  const int lrow8 = l >> 3;
  const int lk8 = (l & 7) * 8;
  f32x4 acc[4][4] = {};

  for (int k0 = 0; k0 < kLen; k0 += 64) {
    __syncthreads();
#pragma unroll
    for (int i = 0; i < 4; ++i) {
      const int ch = w * 4 + i;
      gload16(A + (long)(aRow0 + ch * 8 + lrow8) * lda + k0 + lk8, &As[ch * 512]);
      gload16(BT + (long)(bRow0 + ch * 8 + lrow8) * ldbt + k0 + lk8, &Bs[ch * 512]);
    }
    __syncthreads();
#pragma unroll
    for (int ks = 0; ks < 2; ++ks) {
      bf16x8 av[4], bv[4];
#pragma unroll
      for (int m = 0; m < 4; ++m)
        av[m] = *reinterpret_cast<const bf16x8*>(
            &As[(wr * 64 + m * 16 + (l & 15)) * 64 + ks * 32 + (l >> 4) * 8]);
#pragma unroll
      for (int n = 0; n < 4; ++n)
        bv[n] = *reinterpret_cast<const bf16x8*>(
            &Bs[(wc * 64 + n * 16 + (l & 15)) * 64 + ks * 32 + (l >> 4) * 8]);
#pragma unroll
      for (int m = 0; m < 4; ++m)
#pragma unroll
        for (int n = 0; n < 4; ++n)
          acc[m][n] = __builtin_amdgcn_mfma_f32_16x16x32_bf16(av[m], bv[n], acc[m][n], 0, 0, 0);
    }
  }

  const int lr = (l >> 4) * 4;
  const int lc = l & 15;
#pragma unroll
  for (int m = 0; m < 4; ++m)
#pragma unroll
    for (int n = 0; n < 4; ++n) {
      const int rowb = aRow0 + wr * 64 + m * 16 + lr;
      const int col = bRow0 + wc * 64 + n * 16 + lc;
      if (col < 256) {
#pragma unroll
        for (int j = 0; j < 4; ++j)
          Q0[(long)(rowb + j) * 256 + col] = acc[m][n][j];
      } else {
        unsigned short pv[4];
#pragma unroll
        for (int j = 0; j < 4; ++j) pv[j] = f2bf(dinv[rowb + j] * acc[m][n][j]);
        *reinterpret_cast<ushort4*>(&q12T[(long)(col - 256) * NN + rowb]) =
            *reinterpret_cast<ushort4*>(pv);
      }
    }
}

// ---- reduceA: S = sum_z Pb[z] (= adj_bf @ (dinv.*[q1|q2])) over [8192][512] ----
// c<256: s1[r][c] = dinv[r]*S (f32).  c>=256: bT2[c-256][r] = bf16(dinv[r]^2 * S) (transposed)
__global__ void reduceA_kernel(const unsigned short* __restrict__ Pb, const int ks,
                               const float* __restrict__ dinv,
                               float* __restrict__ s1, unsigned short* __restrict__ bT2) {
  __shared__ float tile[64][65];
  const int c0 = blockIdx.x * 64; // [0,512)
  const int r0 = blockIdx.y * 64;
  const int t = threadIdx.x;
  if (c0 < 256) {
#pragma unroll
    for (int it = 0; it < 16; ++it) {
      int e = it * 256 + t;
      int r = e >> 6, c = e & 63;
      long off = (long)(r0 + r) * 512 + c0 + c;
      float S = 0.f;
      for (int z = 0; z < ks; ++z) S += bf2f(Pb[(long)z * NN * 512 + off]);
      s1[(long)(r0 + r) * 256 + c0 + c] = dinv[r0 + r] * S;
    }
  } else {
#pragma unroll
    for (int it = 0; it < 16; ++it) {
      int e = it * 256 + t;
      int r = e >> 6, c = e & 63;
      long off = (long)(r0 + r) * 512 + c0 + c;
      float S = 0.f;
      for (int z = 0; z < ks; ++z) S += bf2f(Pb[(long)z * NN * 512 + off]);
      const float di = dinv[r0 + r];
      tile[r][c] = di * di * S;
    }
    __syncthreads();
#pragma unroll
    for (int it = 0; it < 16; ++it) {
      int e = it * 256 + t;
      int rr = e >> 6, cc = e & 63;
      bT2[(long)(c0 - 256 + rr) * NN + r0 + cc] = f2bf(tile[cc][rr]);
    }
  }
}

// ---- combine: h = relu(q0 - s1 + 2*dinv[i]*sum_z P_B[z] + cheb_b); v = h @ gc2_W ----
__global__ void combine_u_kernel(const float* __restrict__ Q0, const float* __restrict__ s1,
                                 const unsigned short* __restrict__ Pb, const int ks,
                                 const float* __restrict__ dinv, const float* __restrict__ chebb,
                                 const float* __restrict__ gw, float* __restrict__ v) {
  const int i = blockIdx.x, t = threadIdx.x; // t = hidden channel
  float S = 0.f;
  for (int z = 0; z < ks; ++z) S += bf2f(Pb[(long)z * NN * 256 + (long)i * 256 + t]);
  float hv = Q0[(long)i * 256 + t] - s1[(long)i * 256 + t] + 2.f * dinv[i] * S + chebb[t];
  hv = hv > 0.f ? hv : 0.f;
  float p0 = hv * gw[t * 2];
  float p1 = hv * gw[t * 2 + 1];
  for (int o = 32; o; o >>= 1) {
    p0 += __shfl_down(p0, o, 64);
    p1 += __shfl_down(p1, o, 64);
  }
  __shared__ float s0[4], s1s[4];
  if ((t & 63) == 0) { s0[t >> 6] = p0; s1s[t >> 6] = p1; }
  __syncthreads();
  if (t == 0) {
    v[i * 2] = s0[0] + s0[1] + s0[2] + s0[3];
    v[i * 2 + 1] = s1s[0] + s1s[1] + s1s[2] + s1s[3];
  }
}

// ---- logits: 8 rows per block; logits[i][c] = Abf[i,:] . v[:,c] + gb[c] ----
__global__ void logits8_kernel(const unsigned short* __restrict__ Abf,
                               const float* __restrict__ v,
                               const float* __restrict__ gb, float* __restrict__ logits) {
  const int g = blockIdx.x; // 1024 groups of 8 rows
  const int t = threadIdx.x;
  const float4* vv = reinterpret_cast<const float4*>(v);
  float a0[8] = {}, a1[8] = {};
#pragma unroll
  for (int it = 0; it < 4; ++it) {
    const int idx = it * 256 + t;
    float4 vs[4];
#pragma unroll
    for (int q = 0; q < 4; ++q) vs[q] = vv[idx * 4 + q];
#pragma unroll
    for (int r = 0; r < 8; ++r) {
      uint4 pk = reinterpret_cast<const uint4*>(Abf + (long)(g * 8 + r) * NN)[idx];
      unsigned uu[4] = {pk.x, pk.y, pk.z, pk.w};
#pragma unroll
      for (int q = 0; q < 4; ++q) {
        union { unsigned u; float f; } flo, fhi;
        flo.u = uu[q] << 16;
        fhi.u = uu[q] & 0xFFFF0000u;
        a0[r] += flo.f * vs[q].x + fhi.f * vs[q].z;
        a1[r] += flo.f * vs[q].y + fhi.f * vs[q].w;
      }
    }
  }
  __shared__ float sm0[8][4], sm1[8][4];
#pragma unroll
  for (int r = 0; r < 8; ++r) {
    float x0 = a0[r], x1 = a1[r];
    for (int o = 32; o; o >>= 1) {
      x0 += __shfl_down(x0, o, 64);
      x1 += __shfl_down(x1, o, 64);
    }
    if ((t & 63) == 0) { sm0[r][t >> 6] = x0; sm1[r][t >> 6] = x1; }
  }
  __syncthreads();
  if (t < 8) {
    logits[(g * 8 + t) * 2] = sm0[t][0] + sm0[t][1] + sm0[t][2] + sm0[t][3] + gb[0];
    logits[(g * 8 + t) * 2 + 1] = sm1[t][0] + sm1[t][1] + sm1[t][2] + sm1[t][3] + gb[1];
  }
}

// ---------------- out[c] = max_i logits[i][c] ----------------
__global__ void maxpool_kernel(const float* __restrict__ logits, float* __restrict__ out) {
  const int t = threadIdx.x;
  float m0 = -3.4e38f, m1 = -3.4e38f;
  for (int i = t; i < NN; i += 256) {
    m0 = fmaxf(m0, logits[i * 2]);
    m1 = fmaxf(m1, logits[i * 2 + 1]);
  }
  for (int o = 32; o; o >>= 1) {
    m0 = fmaxf(m0, __shfl_down(m0, o, 64));
    m1 = fmaxf(m1, __shfl_down(m1, o, 64));
  }
  __shared__ float s0[4], s1[4];
  if ((t & 63) == 0) { s0[t >> 6] = m0; s1[t >> 6] = m1; }
  __syncthreads();
  if (t == 0) {
    out[0] = fmaxf(fmaxf(s0[0], s0[1]), fmaxf(s0[2], s0[3]));
    out[1] = fmaxf(fmaxf(s1[0], s1[1]), fmaxf(s1[2], s1[3]));
  }
}

extern "C" void kernel_launch(void* const* d_in, const int* in_sizes, int n_in,
                              void* d_out, int out_size, void* d_ws, size_t ws_size,
                              hipStream_t stream) {
  (void)in_sizes; (void)n_in; (void)out_size;
  const float* x = (const float*)d_in[0];       // [8192,512]
  const float* adj = (const float*)d_in[1];     // [8192,8192]
  const float* cheb_W = (const float*)d_in[2];  // [3,512,256]
  const float* cheb_b = (const float*)d_in[3];  // [256]
  const float* gc2_W = (const float*)d_in[4];   // [256,2]
  const float* gc2_b = (const float*)d_in[5];   // [2]
  float* out = (float*)d_out;                   // [2]

  char* ws = (char*)d_ws;
  unsigned short* Abf  = (unsigned short*)(ws);               // 128 MiB bf16 adj, live to end
  unsigned short* xbf  = (unsigned short*)(ws + 134217728L);  // 8 MiB
  unsigned short* WTc  = (unsigned short*)(ws + 142606336L);  // 768 KiB [768][512]
  float* Q0            = (float*)(ws + 143392768L);           // 8 MiB f32 [8192][256] = x(W0-W2)
  unsigned short* q12T = (unsigned short*)(ws + 151781376L);  // 8 MiB bf16 [512][8192]
  float* s1            = (float*)(ws + 160169984L);           // 8 MiB f32 [8192][256]
  unsigned short* bT2  = (unsigned short*)(ws + 168558592L);  // 4 MiB bf16 [256][8192]
  float* dinv          = (float*)(ws + 172752896L);           // 32 KiB
  float* v             = (float*)(ws + 172785664L);           // 64 KiB
  float* logits        = (float*)(ws + 172851200L);           // 64 KiB
  unsigned short* P    = (unsigned short*)(ws + 172916736L);  // bf16 split-K partials

  const long PBASE = 172916736L;
  int ksA = 1, ksB = 2; // P: max(8 MiB, 8 MiB)
  if (ws_size >= (size_t)(PBASE + 32L * 1048576L)) { ksA = 4; ksB = 8; }
  else if (ws_size >= (size_t)(PBASE + 16L * 1048576L)) { ksA = 2; ksB = 4; }

  // 1) Abf = bf16(adj); dinv = rsqrt(rowsum)
  castadj_deg_kernel<<<dim3(NN), dim3(256), 0, stream>>>(adj, Abf, dinv);
  // 2) xbf = bf16(x); WTc = [W0-W2|W1|W2]^T bf16
  castxbf_kernel<<<dim3(4096), dim3(256), 0, stream>>>(x, xbf);
  buildwt_kernel<<<dim3(1536), dim3(256), 0, stream>>>(cheb_W, WTc);
  // 3) gemm_w: Q = xbf @ Wcat -> Q0 (f32, cols<256), q12T = (dinv.*[q1|q2])^T bf16
  gemm_w<<<dim3(6, 64, 1), dim3(256), 0, stream>>>(xbf, WTc, 512, 512, 512, 768,
      Q0, q12T, dinv);
  // 4) GEMM_A (8-phase): P = split-K bf16 partials of Abf @ (dinv.*[q1|q2])  [8192][512]
  gemm8<<<dim3(2, 32, ksA), dim3(512), 0, stream>>>(Abf, q12T, NN / ksA, 512, P);
  // 5) reduceA: s1 = dinv.*S[:,0:256] f32; bT2 = (dinv^2 .* S[:,256:512])^T bf16
  reduceA_kernel<<<dim3(8, 128), dim3(256), 0, stream>>>(P, ksA, dinv, s1, bT2);
  // 6) GEMM_B (8-phase): P = split-K bf16 partials of Abf @ (dinv.*s2)  [8192][256]
  gemm8<<<dim3(1, 32, ksB), dim3(512), 0, stream>>>(Abf, bT2, NN / ksB, 256, P);
  // 7) h = relu(Q0 - s1 + 2*dinv.*sumP + b); v = h @ gc2_W
  combine_u_kernel<<<dim3(NN), dim3(256), 0, stream>>>(Q0, s1, P, ksB, dinv, cheb_b, gc2_W, v);
  // 8) logits = bf16(adj) @ v + b
  logits8_kernel<<<dim3(1024), dim3(256), 0, stream>>>(Abf, v, gc2_b, logits);
  maxpool_kernel<<<dim3(1), dim3(256), 0, stream>>>(logits, out);
}

// Round 7
// 322.478 us; speedup vs baseline: 1.2560x; 1.0572x over previous
//
#include <hip/hip_runtime.h>
#include <stdint.h>

#define NN 8192
#define NF 512
#define NH 256

typedef __bf16 bf16_t;
typedef bf16_t bf16x8 __attribute__((ext_vector_type(8)));
typedef float f32x4 __attribute__((ext_vector_type(4)));

// round-to-nearest-even f32 -> bf16 bit pattern
__device__ __forceinline__ unsigned short f2bf(float f) {
  union { float f; unsigned u; } v; v.f = f;
  unsigned r = v.u + 0x7FFFu + ((v.u >> 16) & 1u);
  return (unsigned short)(r >> 16);
}

__device__ __forceinline__ float bf2f(unsigned short u) {
  union { unsigned u; float f; } v; v.u = (unsigned)u << 16;
  return v.f;
}

// async global->LDS, 16B per lane; LDS dest is wave-uniform base + lane*16
__device__ __forceinline__ void gload16(const void* g, void* l) {
  __builtin_amdgcn_global_load_lds(
      (__attribute__((address_space(1))) void*)g,
      (__attribute__((address_space(3))) void*)l, 16, 0, 0);
}

// ---- fused: Abf = bf16(adj) raw cast AND dinv = rsqrt(max(rowsum,1e-12)) ----
__global__ void castadj_deg_kernel(const float* __restrict__ adj,
                                   unsigned short* __restrict__ Abf,
                                   float* __restrict__ dinv) {
  const int i = blockIdx.x, t = threadIdx.x;
  const float4* row = reinterpret_cast<const float4*>(adj + (long)i * NN);
  ushort4* orow = reinterpret_cast<ushort4*>(Abf + (long)i * NN);
  float s = 0.f;
#pragma unroll
  for (int it = 0; it < 8; ++it) {
    float4 a = row[it * 256 + t];
    s += a.x + a.y + a.z + a.w;
    ushort4 o;
    o.x = f2bf(a.x); o.y = f2bf(a.y); o.z = f2bf(a.z); o.w = f2bf(a.w);
    orow[it * 256 + t] = o;
  }
  for (int o = 32; o; o >>= 1) s += __shfl_down(s, o, 64);
  __shared__ float sm[4];
  if ((t & 63) == 0) sm[t >> 6] = s;
  __syncthreads();
  if (t == 0) {
    float d = fmaxf(sm[0] + sm[1] + sm[2] + sm[3], 1e-12f);
    dinv[i] = rsqrtf(d);
  }
}

// ---- merged: xbf = bf16(x)  AND  WTc[c][k] (c<256: W0-W2; <512: W1; <768: W2) ----
__global__ void prep_kernel(const float* __restrict__ x, const float* __restrict__ W,
                            unsigned short* __restrict__ xbf, unsigned short* __restrict__ WTc) {
  const int b = blockIdx.x, t = threadIdx.x;
  if (b < 4096) {
    const long idx4 = (long)b * 256 + t;
    float4 a = reinterpret_cast<const float4*>(x)[idx4];
    ushort4 o;
    o.x = f2bf(a.x); o.y = f2bf(a.y); o.z = f2bf(a.z); o.w = f2bf(a.w);
    reinterpret_cast<ushort4*>(xbf)[idx4] = o;
  } else {
    const int idx = (b - 4096) * 256 + t; // 393216
    const int c = idx >> 9, k = idx & 511;
    float val;
    if (c < 256) val = W[k * 256 + c] - W[262144 + k * 256 + c];
    else if (c < 512) val = W[131072 + k * 256 + (c - 256)];
    else val = W[262144 + k * 256 + (c - 512)];
    WTc[(long)c * 512 + k] = f2bf(val);
  }
}

// ================= 2-phase/K-tile 256x256 bf16 GEMM (T2+T4+T5), bf16 partial out =================
// A [M][NN] bf16 row-major; BT [Nout][NN] bf16. C partial = A[:,kz-range]@B.
// 512 thr = 8 waves (2 Mrow x 4 Ncol); wave owns 128x64 = 8x4 frags of 16x16; acc = 128 VGPR.
// LDS: per matrix 2 dbuf x 2 k-half x (256 x 32 k) = 64 KiB; total 128 KiB, 1 blk/CU.
// Per K-tile t, 2 phases (one per k-half), each: 12 ds_read_b128 (8 av + 4 bv) -> 32 MFMA.
//  p0(kh0): stage A,B of t+1.kh1 into [d^1][1]  |  p1(kh1): stage A,B of t+2.kh0 into [d][0]
// Each phase: reads; stage; s_barrier; lgkmcnt(0); setprio(1); 32 MFMA; setprio(0); [vmcnt] barrier.
// vmcnt(4) at p1 end: outstanding = p0(4)+p1(4); waiting to 4 confirms p0's loads (t+1.kh1) landed;
// t+1.kh0 was staged 2 phases earlier -> older, also landed. Per-wave stake + barrier => tile valid.
// Slot overwrites target slots whose last reads completed at the prior phase's lgkmcnt(0)+barrier.
// LDS swizzle (read side XOR, pre-swizzled GLOBAL source, linear LDS dest - rule #21).
__device__ __forceinline__ bf16x8 ldfrag(const unsigned short* h, int r, int l) {
  const int kb = ((l >> 4) * 16) ^ (((r >> 1) & 3) << 4);
  return *reinterpret_cast<const bf16x8*>((const char*)h + r * 64 + kb);
}

__device__ __forceinline__ void stage_half(const unsigned short* __restrict__ G,
                                           int gR0, long kByte, unsigned short* lbase,
                                           int w, int tid) {
  const int rr = tid >> 2;                 // dest row 0..127 (call 0) / +128 (call 1)
  const int kb = (tid & 3) * 16;           // dest byte col within 64B row
  const int sw = ((rr >> 1) & 3) << 4;     // same swizzle for rr+128
  gload16((const char*)(G + (long)(gR0 + rr) * NN) + kByte + (kb ^ sw),
          (char*)lbase + w * 1024);
  gload16((const char*)(G + (long)(gR0 + 128 + rr) * NN) + kByte + (kb ^ sw),
          (char*)lbase + 8192 + w * 1024);
}

#define BAR() __builtin_amdgcn_s_barrier()
#define SCHED0() __builtin_amdgcn_sched_barrier(0)
#define LGKM0() do { asm volatile("s_waitcnt lgkmcnt(0)" ::: "memory"); SCHED0(); } while (0)

__global__ __launch_bounds__(512) void gemm8(
    const unsigned short* __restrict__ A, const unsigned short* __restrict__ BT,
    const int kLen, const int Nout, unsigned short* __restrict__ Pb) {
  __shared__ unsigned short As[2][2][256 * 32];
  __shared__ unsigned short Bs[2][2][256 * 32];
  const int tid = threadIdx.x;
  const int w = tid >> 6, l = tid & 63;
  const int wr = w >> 2, wc = w & 3;
  // XCD-aware chunked swizzle (nwg2d % 8 == 0 for our grids)
  const int nwg2d = gridDim.x * gridDim.y;
  const int lin = blockIdx.x + gridDim.x * blockIdx.y;
  const int wg = (lin & 7) * (nwg2d >> 3) + (lin >> 3);
  const int bx = wg % gridDim.x, by = wg / gridDim.x;
  const int aRow0 = by * 256, bRow0 = bx * 256;
  const long kbegB = (long)blockIdx.z * kLen * 2; // byte offset along K
  const int nt = kLen >> 6;
  f32x4 acc[8][4] = {};

  // prologue: t0.kh0(A,B), t0.kh1(A,B), t1.kh0(A,B) = 12 loads/wave
  stage_half(A, aRow0, kbegB, &As[0][0][0], w, tid);
  stage_half(BT, bRow0, kbegB, &Bs[0][0][0], w, tid);
  stage_half(A, aRow0, kbegB + 64, &As[0][1][0], w, tid);
  stage_half(BT, bRow0, kbegB + 64, &Bs[0][1][0], w, tid);
  {
    const int t1 = (nt > 1) ? 1 : 0;
    stage_half(A, aRow0, kbegB + (long)t1 * 128, &As[1][0][0], w, tid);
    stage_half(BT, bRow0, kbegB + (long)t1 * 128, &Bs[1][0][0], w, tid);
  }
  asm volatile("s_waitcnt vmcnt(4)" ::: "memory"); // tile0 fully landed (own stake)
  SCHED0();
  BAR(); SCHED0();                                 // all waves' stakes -> tile0 valid

  bf16x8 av[8], bv[4];
  const int la = l & 15;
  for (int t = 0; t < nt; ++t) {
    const int d = t & 1;
    const unsigned short* Ah0 = &As[d][0][0];
    const unsigned short* Ah1 = &As[d][1][0];
    const unsigned short* Bh0 = &Bs[d][0][0];
    const unsigned short* Bh1 = &Bs[d][1][0];
    const int tt1 = (t + 1 < nt) ? t + 1 : nt - 1; // clamped (keeps vmcnt counts exact)
    const int tt2 = (t + 2 < nt) ? t + 2 : nt - 1;

    // ---- phase 0: kh0, full 128x64 (32 MFMA) ----
#pragma unroll
    for (int m = 0; m < 8; ++m) av[m] = ldfrag(Ah0, wr * 128 + m * 16 + la, l);
#pragma unroll
    for (int n = 0; n < 4; ++n) bv[n] = ldfrag(Bh0, wc * 64 + n * 16 + la, l);
    stage_half(A, aRow0, kbegB + (long)tt1 * 128 + 64, &As[d ^ 1][1][0], w, tid);
    stage_half(BT, bRow0, kbegB + (long)tt1 * 128 + 64, &Bs[d ^ 1][1][0], w, tid);
    BAR();
    LGKM0();
    __builtin_amdgcn_s_setprio(1);
#pragma unroll
    for (int m = 0; m < 8; ++m)
#pragma unroll
      for (int n = 0; n < 4; ++n)
        acc[m][n] = __builtin_amdgcn_mfma_f32_16x16x32_bf16(av[m], bv[n], acc[m][n], 0, 0, 0);
    __builtin_amdgcn_s_setprio(0);
    BAR(); SCHED0();

    // ---- phase 1: kh1, full 128x64 (32 MFMA) ----
#pragma unroll
    for (int m = 0; m < 8; ++m) av[m] = ldfrag(Ah1, wr * 128 + m * 16 + la, l);
#pragma unroll
    for (int n = 0; n < 4; ++n) bv[n] = ldfrag(Bh1, wc * 64 + n * 16 + la, l);
    stage_half(A, aRow0, kbegB + (long)tt2 * 128, &As[d][0][0], w, tid);
    stage_half(BT, bRow0, kbegB + (long)tt2 * 128, &Bs[d][0][0], w, tid);
    BAR();
    LGKM0();
    __builtin_amdgcn_s_setprio(1);
#pragma unroll
    for (int m = 0; m < 8; ++m)
#pragma unroll
      for (int n = 0; n < 4; ++n)
        acc[m][n] = __builtin_amdgcn_mfma_f32_16x16x32_bf16(av[m], bv[n], acc[m][n], 0, 0, 0);
    __builtin_amdgcn_s_setprio(0);
    asm volatile("s_waitcnt vmcnt(4)" ::: "memory"); // tile t+1 fully landed (own stake)
    SCHED0();
    BAR(); SCHED0();                                 // all waves -> t+1 valid
  }

  // C elem (row = base + (l>>4)*4 + j, col = base + (l&15))  [m89-verified]
  unsigned short* Pk = Pb + (long)blockIdx.z * NN * Nout;
  const int lr = (l >> 4) * 4;
#pragma unroll
  for (int m = 0; m < 8; ++m)
#pragma unroll
    for (int n = 0; n < 4; ++n) {
      const int rowb = aRow0 + wr * 128 + m * 16 + lr;
      const int col = bRow0 + wc * 64 + n * 16 + la;
#pragma unroll
      for (int j = 0; j < 4; ++j)
        Pk[(long)(rowb + j) * Nout + col] = f2bf(acc[m][n][j]);
    }
}

// ---------------- m97-style 128x128 bf16 GEMM, used only for the small W-projection ----------------
// Epilogue: col<256 -> Q0[row][col] f32; col>=256 -> q12T[col-256][row] = bf16(dinv[row]*v)
__global__ __launch_bounds__(256) void gemm_w(
    const unsigned short* __restrict__ A, const unsigned short* __restrict__ BT,
    const int lda, const int ldbt, const int kLen, const int Nout,
    float* __restrict__ Q0, unsigned short* __restrict__ q12T,
    const float* __restrict__ dinv) {
  __shared__ unsigned short As[128 * 64];
  __shared__ unsigned short Bs[128 * 64];
  const int tid = threadIdx.x;
  const int w = tid >> 6, l = tid & 63;
  const int wr = w >> 1, wc = w & 1;
  const int nwg2d = gridDim.x * gridDim.y;
  const int lin = blockIdx.x + gridDim.x * blockIdx.y;
  const int wg = (lin & 7) * (nwg2d >> 3) + (lin >> 3);
  const int bx = wg % gridDim.x, by = wg / gridDim.x;
  const int aRow0 = by * 128, bRow0 = bx * 128;
  const int lrow8 = l >> 3;
  const int lk8 = (l & 7) * 8;
  f32x4 acc[4][4] = {};

  for (int k0 = 0; k0 < kLen; k0 += 64) {
    __syncthreads();
#pragma unroll
    for (int i = 0; i < 4; ++i) {
      const int ch = w * 4 + i;
      gload16(A + (long)(aRow0 + ch * 8 + lrow8) * lda + k0 + lk8, &As[ch * 512]);
      gload16(BT + (long)(bRow0 + ch * 8 + lrow8) * ldbt + k0 + lk8, &Bs[ch * 512]);
    }
    __syncthreads();
#pragma unroll
    for (int ks = 0; ks < 2; ++ks) {
      bf16x8 av[4], bv[4];
#pragma unroll
      for (int m = 0; m < 4; ++m)
        av[m] = *reinterpret_cast<const bf16x8*>(
            &As[(wr * 64 + m * 16 + (l & 15)) * 64 + ks * 32 + (l >> 4) * 8]);
#pragma unroll
      for (int n = 0; n < 4; ++n)
        bv[n] = *reinterpret_cast<const bf16x8*>(
            &Bs[(wc * 64 + n * 16 + (l & 15)) * 64 + ks * 32 + (l >> 4) * 8]);
#pragma unroll
      for (int m = 0; m < 4; ++m)
#pragma unroll
        for (int n = 0; n < 4; ++n)
          acc[m][n] = __builtin_amdgcn_mfma_f32_16x16x32_bf16(av[m], bv[n], acc[m][n], 0, 0, 0);
    }
  }

  const int lr = (l >> 4) * 4;
  const int lc = l & 15;
#pragma unroll
  for (int m = 0; m < 4; ++m)
#pragma unroll
    for (int n = 0; n < 4; ++n) {
      const int rowb = aRow0 + wr * 64 + m * 16 + lr;
      const int col = bRow0 + wc * 64 + n * 16 + lc;
      if (col < 256) {
#pragma unroll
        for (int j = 0; j < 4; ++j)
          Q0[(long)(rowb + j) * 256 + col] = acc[m][n][j];
      } else {
        unsigned short pv[4];
#pragma unroll
        for (int j = 0; j < 4; ++j) pv[j] = f2bf(dinv[rowb + j] * acc[m][n][j]);
        *reinterpret_cast<ushort4*>(&q12T[(long)(col - 256) * NN + rowb]) =
            *reinterpret_cast<ushort4*>(pv);
      }
    }
}

// ---- reduceA: S = sum_z Pb[z] (= adj_bf @ (dinv.*[q1|q2])) over [8192][512] ----
// c<256: s1[r][c] = dinv[r]*S (f32).  c>=256: bT2[c-256][r] = bf16(dinv[r]^2 * S) (transposed)
__global__ void reduceA_kernel(const unsigned short* __restrict__ Pb, const int ks,
                               const float* __restrict__ dinv,
                               float* __restrict__ s1, unsigned short* __restrict__ bT2) {
  __shared__ float tile[64][65];
  const int c0 = blockIdx.x * 64; // [0,512)
  const int r0 = blockIdx.y * 64;
  const int t = threadIdx.x;
  if (c0 < 256) {
#pragma unroll
    for (int it = 0; it < 16; ++it) {
      int e = it * 256 + t;
      int r = e >> 6, c = e & 63;
      long off = (long)(r0 + r) * 512 + c0 + c;
      float S = 0.f;
      for (int z = 0; z < ks; ++z) S += bf2f(Pb[(long)z * NN * 512 + off]);
      s1[(long)(r0 + r) * 256 + c0 + c] = dinv[r0 + r] * S;
    }
  } else {
#pragma unroll
    for (int it = 0; it < 16; ++it) {
      int e = it * 256 + t;
      int r = e >> 6, c = e & 63;
      long off = (long)(r0 + r) * 512 + c0 + c;
      float S = 0.f;
      for (int z = 0; z < ks; ++z) S += bf2f(Pb[(long)z * NN * 512 + off]);
      const float di = dinv[r0 + r];
      tile[r][c] = di * di * S;
    }
    __syncthreads();
#pragma unroll
    for (int it = 0; it < 16; ++it) {
      int e = it * 256 + t;
      int rr = e >> 6, cc = e & 63;
      bT2[(long)(c0 - 256 + rr) * NN + r0 + cc] = f2bf(tile[cc][rr]);
    }
  }
}

// ---- combine: h = relu(q0 - s1 + 2*dinv[i]*sum_z P_B[z] + cheb_b); v = h @ gc2_W ----
__global__ void combine_u_kernel(const float* __restrict__ Q0, const float* __restrict__ s1,
                                 const unsigned short* __restrict__ Pb, const int ks,
                                 const float* __restrict__ dinv, const float* __restrict__ chebb,
                                 const float* __restrict__ gw, float* __restrict__ v) {
  const int i = blockIdx.x, t = threadIdx.x; // t = hidden channel
  float S = 0.f;
  for (int z = 0; z < ks; ++z) S += bf2f(Pb[(long)z * NN * 256 + (long)i * 256 + t]);
  float hv = Q0[(long)i * 256 + t] - s1[(long)i * 256 + t] + 2.f * dinv[i] * S + chebb[t];
  hv = hv > 0.f ? hv : 0.f;
  float p0 = hv * gw[t * 2];
  float p1 = hv * gw[t * 2 + 1];
  for (int o = 32; o; o >>= 1) {
    p0 += __shfl_down(p0, o, 64);
    p1 += __shfl_down(p1, o, 64);
  }
  __shared__ float s0[4], s1s[4];
  if ((t & 63) == 0) { s0[t >> 6] = p0; s1s[t >> 6] = p1; }
  __syncthreads();
  if (t == 0) {
    v[i * 2] = s0[0] + s0[1] + s0[2] + s0[3];
    v[i * 2 + 1] = s1s[0] + s1s[1] + s1s[2] + s1s[3];
  }
}

// ---- logits: 8 rows per block; logits[i][c] = Abf[i,:] . v[:,c] + gb[c] ----
__global__ void logits8_kernel(const unsigned short* __restrict__ Abf,
                               const float* __restrict__ v,
                               const float* __restrict__ gb, float* __restrict__ logits) {
  const int g = blockIdx.x; // 1024 groups of 8 rows
  const int t = threadIdx.x;
  const float4* vv = reinterpret_cast<const float4*>(v);
  float a0[8] = {}, a1[8] = {};
#pragma unroll
  for (int it = 0; it < 4; ++it) {
    const int idx = it * 256 + t;
    float4 vs[4];
#pragma unroll
    for (int q = 0; q < 4; ++q) vs[q] = vv[idx * 4 + q];
#pragma unroll
    for (int r = 0; r < 8; ++r) {
      uint4 pk = reinterpret_cast<const uint4*>(Abf + (long)(g * 8 + r) * NN)[idx];
      unsigned uu[4] = {pk.x, pk.y, pk.z, pk.w};
#pragma unroll
      for (int q = 0; q < 4; ++q) {
        union { unsigned u; float f; } flo, fhi;
        flo.u = uu[q] << 16;
        fhi.u = uu[q] & 0xFFFF0000u;
        a0[r] += flo.f * vs[q].x + fhi.f * vs[q].z;
        a1[r] += flo.f * vs[q].y + fhi.f * vs[q].w;
      }
    }
  }
  __shared__ float sm0[8][4], sm1[8][4];
#pragma unroll
  for (int r = 0; r < 8; ++r) {
    float x0 = a0[r], x1 = a1[r];
    for (int o = 32; o; o >>= 1) {
      x0 += __shfl_down(x0, o, 64);
      x1 += __shfl_down(x1, o, 64);
    }
    if ((t & 63) == 0) { sm0[r][t >> 6] = x0; sm1[r][t >> 6] = x1; }
  }
  __syncthreads();
  if (t < 8) {
    logits[(g * 8 + t) * 2] = sm0[t][0] + sm0[t][1] + sm0[t][2] + sm0[t][3] + gb[0];
    logits[(g * 8 + t) * 2 + 1] = sm1[t][0] + sm1[t][1] + sm1[t][2] + sm1[t][3] + gb[1];
  }
}

// ---------------- out[c] = max_i logits[i][c] ----------------
__global__ void maxpool_kernel(const float* __restrict__ logits, float* __restrict__ out) {
  const int t = threadIdx.x;
  float m0 = -3.4e38f, m1 = -3.4e38f;
  for (int i = t; i < NN; i += 256) {
    m0 = fmaxf(m0, logits[i * 2]);
    m1 = fmaxf(m1, logits[i * 2 + 1]);
  }
  for (int o = 32; o; o >>= 1) {
    m0 = fmaxf(m0, __shfl_down(m0, o, 64));
    m1 = fmaxf(m1, __shfl_down(m1, o, 64));
  }
  __shared__ float s0[4], s1[4];
  if ((t & 63) == 0) { s0[t >> 6] = m0; s1[t >> 6] = m1; }
  __syncthreads();
  if (t == 0) {
    out[0] = fmaxf(fmaxf(s0[0], s0[1]), fmaxf(s0[2], s0[3]));
    out[1] = fmaxf(fmaxf(s1[0], s1[1]), fmaxf(s1[2], s1[3]));
  }
}

extern "C" void kernel_launch(void* const* d_in, const int* in_sizes, int n_in,
                              void* d_out, int out_size, void* d_ws, size_t ws_size,
                              hipStream_t stream) {
  (void)in_sizes; (void)n_in; (void)out_size;
  const float* x = (const float*)d_in[0];       // [8192,512]
  const float* adj = (const float*)d_in[1];     // [8192,8192]
  const float* cheb_W = (const float*)d_in[2];  // [3,512,256]
  const float* cheb_b = (const float*)d_in[3];  // [256]
  const float* gc2_W = (const float*)d_in[4];   // [256,2]
  const float* gc2_b = (const float*)d_in[5];   // [2]
  float* out = (float*)d_out;                   // [2]

  char* ws = (char*)d_ws;
  unsigned short* Abf  = (unsigned short*)(ws);               // 128 MiB bf16 adj, live to end
  unsigned short* xbf  = (unsigned short*)(ws + 134217728L);  // 8 MiB
  unsigned short* WTc  = (unsigned short*)(ws + 142606336L);  // 768 KiB [768][512]
  float* Q0            = (float*)(ws + 143392768L);           // 8 MiB f32 [8192][256] = x(W0-W2)
  unsigned short* q12T = (unsigned short*)(ws + 151781376L);  // 8 MiB bf16 [512][8192]
  float* s1            = (float*)(ws + 160169984L);           // 8 MiB f32 [8192][256]
  unsigned short* bT2  = (unsigned short*)(ws + 168558592L);  // 4 MiB bf16 [256][8192]
  float* dinv          = (float*)(ws + 172752896L);           // 32 KiB
  float* v             = (float*)(ws + 172785664L);           // 64 KiB
  float* logits        = (float*)(ws + 172851200L);           // 64 KiB
  unsigned short* P    = (unsigned short*)(ws + 172916736L);  // bf16 split-K partials

  const long PBASE = 172916736L;
  int ksA = 1, ksB = 2; // P: max(8 MiB, 8 MiB)
  if (ws_size >= (size_t)(PBASE + 32L * 1048576L)) { ksA = 4; ksB = 8; }
  else if (ws_size >= (size_t)(PBASE + 16L * 1048576L)) { ksA = 2; ksB = 4; }

  // 1) Abf = bf16(adj); dinv = rsqrt(rowsum)
  castadj_deg_kernel<<<dim3(NN), dim3(256), 0, stream>>>(adj, Abf, dinv);
  // 2) xbf = bf16(x); WTc = [W0-W2|W1|W2]^T bf16  (merged)
  prep_kernel<<<dim3(5632), dim3(256), 0, stream>>>(x, cheb_W, xbf, WTc);
  // 3) gemm_w: Q = xbf @ Wcat -> Q0 (f32, cols<256), q12T = (dinv.*[q1|q2])^T bf16
  gemm_w<<<dim3(6, 64, 1), dim3(256), 0, stream>>>(xbf, WTc, 512, 512, 512, 768,
      Q0, q12T, dinv);
  // 4) GEMM_A (2-phase/tile): P = split-K bf16 partials of Abf @ (dinv.*[q1|q2])  [8192][512]
  gemm8<<<dim3(2, 32, ksA), dim3(512), 0, stream>>>(Abf, q12T, NN / ksA, 512, P);
  // 5) reduceA: s1 = dinv.*S[:,0:256] f32; bT2 = (dinv^2 .* S[:,256:512])^T bf16
  reduceA_kernel<<<dim3(8, 128), dim3(256), 0, stream>>>(P, ksA, dinv, s1, bT2);
  // 6) GEMM_B (2-phase/tile): P = split-K bf16 partials of Abf @ (dinv.*s2)  [8192][256]
  gemm8<<<dim3(1, 32, ksB), dim3(512), 0, stream>>>(Abf, bT2, NN / ksB, 256, P);
  // 7) h = relu(Q0 - s1 + 2*dinv.*sumP + b); v = h @ gc2_W
  combine_u_kernel<<<dim3(NN), dim3(256), 0, stream>>>(Q0, s1, P, ksB, dinv, cheb_b, gc2_W, v);
  // 8) logits = bf16(adj) @ v + b
  logits8_kernel<<<dim3(1024), dim3(256), 0, stream>>>(Abf, v, gc2_b, logits);
  maxpool_kernel<<<dim3(1), dim3(256), 0, stream>>>(logits, out);
}

// Round 8
// 310.994 us; speedup vs baseline: 1.3024x; 1.0369x over previous
//
#include <hip/hip_runtime.h>
#include <stdint.h>

#define NN 8192
#define NF 512
#define NH 256

typedef __bf16 bf16_t;
typedef bf16_t bf16x8 __attribute__((ext_vector_type(8)));
typedef float f32x4 __attribute__((ext_vector_type(4)));

// round-to-nearest-even f32 -> bf16 bit pattern
__device__ __forceinline__ unsigned short f2bf(float f) {
  union { float f; unsigned u; } v; v.f = f;
  unsigned r = v.u + 0x7FFFu + ((v.u >> 16) & 1u);
  return (unsigned short)(r >> 16);
}

__device__ __forceinline__ float bf2f(unsigned short u) {
  union { unsigned u; float f; } v; v.u = (unsigned)u << 16;
  return v.f;
}

// async global->LDS, 16B per lane; LDS dest is wave-uniform base + lane*16
__device__ __forceinline__ void gload16(const void* g, void* l) {
  __builtin_amdgcn_global_load_lds(
      (__attribute__((address_space(1))) void*)g,
      (__attribute__((address_space(3))) void*)l, 16, 0, 0);
}

// ---- fused prep: [0,8192): Abf=bf16(adj) + dinv; [8192,12288): xbf; [12288,13824): WTc ----
__global__ void fusedprep_kernel(const float* __restrict__ adj, const float* __restrict__ x,
                                 const float* __restrict__ W,
                                 unsigned short* __restrict__ Abf, float* __restrict__ dinv,
                                 unsigned short* __restrict__ xbf,
                                 unsigned short* __restrict__ WTc) {
  const int b = blockIdx.x, t = threadIdx.x;
  if (b < 8192) {
    const int i = b;
    const float4* row = reinterpret_cast<const float4*>(adj + (long)i * NN);
    ushort4* orow = reinterpret_cast<ushort4*>(Abf + (long)i * NN);
    float s = 0.f;
#pragma unroll
    for (int it = 0; it < 8; ++it) {
      float4 a = row[it * 256 + t];
      s += a.x + a.y + a.z + a.w;
      ushort4 o;
      o.x = f2bf(a.x); o.y = f2bf(a.y); o.z = f2bf(a.z); o.w = f2bf(a.w);
      orow[it * 256 + t] = o;
    }
    for (int o = 32; o; o >>= 1) s += __shfl_down(s, o, 64);
    __shared__ float sm[4];
    if ((t & 63) == 0) sm[t >> 6] = s;
    __syncthreads();
    if (t == 0) {
      float d = fmaxf(sm[0] + sm[1] + sm[2] + sm[3], 1e-12f);
      dinv[i] = rsqrtf(d);
    }
  } else if (b < 12288) {
    const long idx4 = (long)(b - 8192) * 256 + t;
    float4 a = reinterpret_cast<const float4*>(x)[idx4];
    ushort4 o;
    o.x = f2bf(a.x); o.y = f2bf(a.y); o.z = f2bf(a.z); o.w = f2bf(a.w);
    reinterpret_cast<ushort4*>(xbf)[idx4] = o;
  } else {
    const int idx = (b - 12288) * 256 + t; // 393216
    const int c = idx >> 9, k = idx & 511;
    float val;
    if (c < 256) val = W[k * 256 + c] - W[262144 + k * 256 + c];
    else if (c < 512) val = W[131072 + k * 256 + (c - 256)];
    else val = W[262144 + k * 256 + (c - 512)];
    WTc[(long)c * 512 + k] = f2bf(val);
  }
}

// ================= 256x256 bf16 GEMM, 2-barrier/tile interleaved schedule =================
// A [M][NN] bf16 row-major; BT [Nout][NN] bf16. C partial = A[:,kz-range]@B.
// 512 thr = 8 waves (2 Mrow x 4 Ncol); wave owns 128x64 = 8x4 frags of 16x16; acc = 128 VGPR.
// LDS: per matrix 2 dbuf x 2 k-half x (256 x 32 k) = 64 KiB; total 128 KiB, 1 blk/CU.
// Per K-tile t: {kh0 reads; early-stage t+1.kh1; lgkm0; BAR(mid); late-stage t+2.kh0->[d][0];
//   MFMA-kh0 with av-kh1 reloads interleaved; bv-kh1 reloads; lgkm0; MFMA-kh1 (pure, setprio);
//   vmcnt(4); BAR(end)}.
// Safety: [d][0] overwrite OK after BAR(mid) (all waves' lgkm#1 done); [d][1] overwrite (next
// tile's early stage) OK after BAR(end) (all waves' lgkm#2 done). vmcnt(4) at end: outstanding
// <= {t+1.kh0, t+1.kh1, t+2.kh0}; wait-to-4 leaves t+2.kh0 -> both t+1 halves landed; per-wave
// stake + BAR(end) publishes. All crossings pinned by "memory"-clobber asm + sched_barrier(0).
// LDS swizzle: read-side XOR + pre-swizzled GLOBAL source, linear LDS dest (rule #21).
__device__ __forceinline__ bf16x8 ldfrag(const unsigned short* h, int r, int l) {
  const int kb = ((l >> 4) * 16) ^ (((r >> 1) & 3) << 4);
  return *reinterpret_cast<const bf16x8*>((const char*)h + r * 64 + kb);
}

__device__ __forceinline__ void stage_half(const unsigned short* __restrict__ G,
                                           int gR0, long kByte, unsigned short* lbase,
                                           int w, int tid) {
  const int rr = tid >> 2;                 // dest row 0..127 (call 0) / +128 (call 1)
  const int kb = (tid & 3) * 16;           // dest byte col within 64B row
  const int sw = ((rr >> 1) & 3) << 4;     // same swizzle for rr+128
  gload16((const char*)(G + (long)(gR0 + rr) * NN) + kByte + (kb ^ sw),
          (char*)lbase + w * 1024);
  gload16((const char*)(G + (long)(gR0 + 128 + rr) * NN) + kByte + (kb ^ sw),
          (char*)lbase + 8192 + w * 1024);
}

#define BAR() __builtin_amdgcn_s_barrier()
#define SCHED0() __builtin_amdgcn_sched_barrier(0)
#define LGKM0() do { asm volatile("s_waitcnt lgkmcnt(0)" ::: "memory"); SCHED0(); } while (0)

__global__ __launch_bounds__(512) void gemm8(
    const unsigned short* __restrict__ A, const unsigned short* __restrict__ BT,
    const int kLen, const int Nout, unsigned short* __restrict__ Pb) {
  __shared__ unsigned short As[2][2][256 * 32];
  __shared__ unsigned short Bs[2][2][256 * 32];
  const int tid = threadIdx.x;
  const int w = tid >> 6, l = tid & 63;
  const int wr = w >> 2, wc = w & 3;
  // XCD-aware chunked swizzle (nwg2d % 8 == 0 for our grids)
  const int nwg2d = gridDim.x * gridDim.y;
  const int lin = blockIdx.x + gridDim.x * blockIdx.y;
  const int wg = (lin & 7) * (nwg2d >> 3) + (lin >> 3);
  const int bx = wg % gridDim.x, by = wg / gridDim.x;
  const int aRow0 = by * 256, bRow0 = bx * 256;
  const long kbegB = (long)blockIdx.z * kLen * 2; // byte offset along K
  const int nt = kLen >> 6;
  f32x4 acc[8][4] = {};

  // prologue: t0.kh0(A,B), t0.kh1(A,B), t1.kh0(A,B) = 12 loads/wave (issue order matters)
  stage_half(A, aRow0, kbegB, &As[0][0][0], w, tid);
  stage_half(BT, bRow0, kbegB, &Bs[0][0][0], w, tid);
  stage_half(A, aRow0, kbegB + 64, &As[0][1][0], w, tid);
  stage_half(BT, bRow0, kbegB + 64, &Bs[0][1][0], w, tid);
  {
    const int t1 = (nt > 1) ? 1 : 0;
    stage_half(A, aRow0, kbegB + (long)t1 * 128, &As[1][0][0], w, tid);
    stage_half(BT, bRow0, kbegB + (long)t1 * 128, &Bs[1][0][0], w, tid);
  }
  asm volatile("s_waitcnt vmcnt(4)" ::: "memory"); // tile0 fully landed (own stake)
  SCHED0();
  BAR(); SCHED0();                                 // all waves' stakes -> tile0 valid

  bf16x8 av[8], bv[4];
  const int la = l & 15;
  for (int t = 0; t < nt; ++t) {
    const int d = t & 1;
    const unsigned short* Ah0 = &As[d][0][0];
    const unsigned short* Ah1 = &As[d][1][0];
    const unsigned short* Bh0 = &Bs[d][0][0];
    const unsigned short* Bh1 = &Bs[d][1][0];
    const int tt1 = (t + 1 < nt) ? t + 1 : nt - 1; // clamped (keeps vmcnt counts exact)
    const int tt2 = (t + 2 < nt) ? t + 2 : nt - 1;

    // kh0 fragment reads
#pragma unroll
    for (int m = 0; m < 8; ++m) av[m] = ldfrag(Ah0, wr * 128 + m * 16 + la, l);
#pragma unroll
    for (int n = 0; n < 4; ++n) bv[n] = ldfrag(Bh0, wc * 64 + n * 16 + la, l);
    // early stage: t+1.kh1 -> [d^1][1]
    stage_half(A, aRow0, kbegB + (long)tt1 * 128 + 64, &As[d ^ 1][1][0], w, tid);
    stage_half(BT, bRow0, kbegB + (long)tt1 * 128 + 64, &Bs[d ^ 1][1][0], w, tid);
    LGKM0();                  // own kh0 reads in regs
    BAR(); SCHED0();          // all waves' kh0 reads done -> [d][0] overwrite-safe
    // late stage: t+2.kh0 -> [d][0] (overlaps MFMA below)
    stage_half(A, aRow0, kbegB + (long)tt2 * 128, &As[d][0][0], w, tid);
    stage_half(BT, bRow0, kbegB + (long)tt2 * 128, &Bs[d][0][0], w, tid);
    // MFMA kh0, av reloads for kh1 interleaved after each m's last use
    __builtin_amdgcn_s_setprio(1);
#pragma unroll
    for (int m = 0; m < 8; ++m) {
#pragma unroll
      for (int n = 0; n < 4; ++n)
        acc[m][n] = __builtin_amdgcn_mfma_f32_16x16x32_bf16(av[m], bv[n], acc[m][n], 0, 0, 0);
      av[m] = ldfrag(Ah1, wr * 128 + m * 16 + la, l);
    }
    __builtin_amdgcn_s_setprio(0);
#pragma unroll
    for (int n = 0; n < 4; ++n) bv[n] = ldfrag(Bh1, wc * 64 + n * 16 + la, l);
    LGKM0();                  // kh1 frags in regs
    __builtin_amdgcn_s_setprio(1);
#pragma unroll
    for (int m = 0; m < 8; ++m)
#pragma unroll
      for (int n = 0; n < 4; ++n)
        acc[m][n] = __builtin_amdgcn_mfma_f32_16x16x32_bf16(av[m], bv[n], acc[m][n], 0, 0, 0);
    __builtin_amdgcn_s_setprio(0);
    asm volatile("s_waitcnt vmcnt(4)" ::: "memory"); // t+1 both halves landed (own stake)
    SCHED0();
    BAR(); SCHED0();                                 // all waves -> t+1 valid; [d][1] safe
  }

  // C elem (row = base + (l>>4)*4 + j, col = base + (l&15))  [m89-verified]
  unsigned short* Pk = Pb + (long)blockIdx.z * NN * Nout;
  const int lr = (l >> 4) * 4;
#pragma unroll
  for (int m = 0; m < 8; ++m)
#pragma unroll
    for (int n = 0; n < 4; ++n) {
      const int rowb = aRow0 + wr * 128 + m * 16 + lr;
      const int col = bRow0 + wc * 64 + n * 16 + la;
#pragma unroll
      for (int j = 0; j < 4; ++j)
        Pk[(long)(rowb + j) * Nout + col] = f2bf(acc[m][n][j]);
    }
}

// ---------------- m97-style 128x128 bf16 GEMM, used only for the small W-projection ----------------
// Epilogue: col<256 -> Q0[row][col] f32; col>=256 -> q12T[col-256][row] = bf16(dinv[row]*v)
__global__ __launch_bounds__(256) void gemm_w(
    const unsigned short* __restrict__ A, const unsigned short* __restrict__ BT,
    const int lda, const int ldbt, const int kLen, const int Nout,
    float* __restrict__ Q0, unsigned short* __restrict__ q12T,
    const float* __restrict__ dinv) {
  __shared__ unsigned short As[128 * 64];
  __shared__ unsigned short Bs[128 * 64];
  const int tid = threadIdx.x;
  const int w = tid >> 6, l = tid & 63;
  const int wr = w >> 1, wc = w & 1;
  const int nwg2d = gridDim.x * gridDim.y;
  const int lin = blockIdx.x + gridDim.x * blockIdx.y;
  const int wg = (lin & 7) * (nwg2d >> 3) + (lin >> 3);
  const int bx = wg % gridDim.x, by = wg / gridDim.x;
  const int aRow0 = by * 128, bRow0 = bx * 128;
  const int lrow8 = l >> 3;
  const int lk8 = (l & 7) * 8;
  f32x4 acc[4][4] = {};

  for (int k0 = 0; k0 < kLen; k0 += 64) {
    __syncthreads();
#pragma unroll
    for (int i = 0; i < 4; ++i) {
      const int ch = w * 4 + i;
      gload16(A + (long)(aRow0 + ch * 8 + lrow8) * lda + k0 + lk8, &As[ch * 512]);
      gload16(BT + (long)(bRow0 + ch * 8 + lrow8) * ldbt + k0 + lk8, &Bs[ch * 512]);
    }
    __syncthreads();
#pragma unroll
    for (int ks = 0; ks < 2; ++ks) {
      bf16x8 av[4], bv[4];
#pragma unroll
      for (int m = 0; m < 4; ++m)
        av[m] = *reinterpret_cast<const bf16x8*>(
            &As[(wr * 64 + m * 16 + (l & 15)) * 64 + ks * 32 + (l >> 4) * 8]);
#pragma unroll
      for (int n = 0; n < 4; ++n)
        bv[n] = *reinterpret_cast<const bf16x8*>(
            &Bs[(wc * 64 + n * 16 + (l & 15)) * 64 + ks * 32 + (l >> 4) * 8]);
#pragma unroll
      for (int m = 0; m < 4; ++m)
#pragma unroll
        for (int n = 0; n < 4; ++n)
          acc[m][n] = __builtin_amdgcn_mfma_f32_16x16x32_bf16(av[m], bv[n], acc[m][n], 0, 0, 0);
    }
  }

  const int lr = (l >> 4) * 4;
  const int lc = l & 15;
#pragma unroll
  for (int m = 0; m < 4; ++m)
#pragma unroll
    for (int n = 0; n < 4; ++n) {
      const int rowb = aRow0 + wr * 64 + m * 16 + lr;
      const int col = bRow0 + wc * 64 + n * 16 + lc;
      if (col < 256) {
#pragma unroll
        for (int j = 0; j < 4; ++j)
          Q0[(long)(rowb + j) * 256 + col] = acc[m][n][j];
      } else {
        unsigned short pv[4];
#pragma unroll
        for (int j = 0; j < 4; ++j) pv[j] = f2bf(dinv[rowb + j] * acc[m][n][j]);
        *reinterpret_cast<ushort4*>(&q12T[(long)(col - 256) * NN + rowb]) =
            *reinterpret_cast<ushort4*>(pv);
      }
    }
}

// ---- reduceA: S = sum_z Pb[z] (= adj_bf @ (dinv.*[q1|q2])) over [8192][512] ----
// c<256: s1[r][c] = dinv[r]*S (f32).  c>=256: bT2[c-256][r] = bf16(dinv[r]^2 * S) (transposed)
__global__ void reduceA_kernel(const unsigned short* __restrict__ Pb, const int ks,
                               const float* __restrict__ dinv,
                               float* __restrict__ s1, unsigned short* __restrict__ bT2) {
  __shared__ float tile[64][65];
  const int c0 = blockIdx.x * 64; // [0,512)
  const int r0 = blockIdx.y * 64;
  const int t = threadIdx.x;
  if (c0 < 256) {
#pragma unroll
    for (int it = 0; it < 16; ++it) {
      int e = it * 256 + t;
      int r = e >> 6, c = e & 63;
      long off = (long)(r0 + r) * 512 + c0 + c;
      float S = 0.f;
      for (int z = 0; z < ks; ++z) S += bf2f(Pb[(long)z * NN * 512 + off]);
      s1[(long)(r0 + r) * 256 + c0 + c] = dinv[r0 + r] * S;
    }
  } else {
#pragma unroll
    for (int it = 0; it < 16; ++it) {
      int e = it * 256 + t;
      int r = e >> 6, c = e & 63;
      long off = (long)(r0 + r) * 512 + c0 + c;
      float S = 0.f;
      for (int z = 0; z < ks; ++z) S += bf2f(Pb[(long)z * NN * 512 + off]);
      const float di = dinv[r0 + r];
      tile[r][c] = di * di * S;
    }
    __syncthreads();
#pragma unroll
    for (int it = 0; it < 16; ++it) {
      int e = it * 256 + t;
      int rr = e >> 6, cc = e & 63;
      bT2[(long)(c0 - 256 + rr) * NN + r0 + cc] = f2bf(tile[cc][rr]);
    }
  }
}

// ---- combine: h = relu(q0 - s1 + 2*dinv[i]*sum_z P_B[z] + cheb_b); v = h @ gc2_W ----
__global__ void combine_u_kernel(const float* __restrict__ Q0, const float* __restrict__ s1,
                                 const unsigned short* __restrict__ Pb, const int ks,
                                 const float* __restrict__ dinv, const float* __restrict__ chebb,
                                 const float* __restrict__ gw, float* __restrict__ v) {
  const int i = blockIdx.x, t = threadIdx.x; // t = hidden channel
  float S = 0.f;
  for (int z = 0; z < ks; ++z) S += bf2f(Pb[(long)z * NN * 256 + (long)i * 256 + t]);
  float hv = Q0[(long)i * 256 + t] - s1[(long)i * 256 + t] + 2.f * dinv[i] * S + chebb[t];
  hv = hv > 0.f ? hv : 0.f;
  float p0 = hv * gw[t * 2];
  float p1 = hv * gw[t * 2 + 1];
  for (int o = 32; o; o >>= 1) {
    p0 += __shfl_down(p0, o, 64);
    p1 += __shfl_down(p1, o, 64);
  }
  __shared__ float s0[4], s1s[4];
  if ((t & 63) == 0) { s0[t >> 6] = p0; s1s[t >> 6] = p1; }
  __syncthreads();
  if (t == 0) {
    v[i * 2] = s0[0] + s0[1] + s0[2] + s0[3];
    v[i * 2 + 1] = s1s[0] + s1s[1] + s1s[2] + s1s[3];
  }
}

// ---- logits: 8 rows per block; logits[i][c] = Abf[i,:] . v[:,c] + gb[c] ----
__global__ void logits8_kernel(const unsigned short* __restrict__ Abf,
                               const float* __restrict__ v,
                               const float* __restrict__ gb, float* __restrict__ logits) {
  const int g = blockIdx.x; // 1024 groups of 8 rows
  const int t = threadIdx.x;
  const float4* vv = reinterpret_cast<const float4*>(v);
  float a0[8] = {}, a1[8] = {};
#pragma unroll
  for (int it = 0; it < 4; ++it) {
    const int idx = it * 256 + t;
    float4 vs[4];
#pragma unroll
    for (int q = 0; q < 4; ++q) vs[q] = vv[idx * 4 + q];
#pragma unroll
    for (int r = 0; r < 8; ++r) {
      uint4 pk = reinterpret_cast<const uint4*>(Abf + (long)(g * 8 + r) * NN)[idx];
      unsigned uu[4] = {pk.x, pk.y, pk.z, pk.w};
#pragma unroll
      for (int q = 0; q < 4; ++q) {
        union { unsigned u; float f; } flo, fhi;
        flo.u = uu[q] << 16;
        fhi.u = uu[q] & 0xFFFF0000u;
        a0[r] += flo.f * vs[q].x + fhi.f * vs[q].z;
        a1[r] += flo.f * vs[q].y + fhi.f * vs[q].w;
      }
    }
  }
  __shared__ float sm0[8][4], sm1[8][4];
#pragma unroll
  for (int r = 0; r < 8; ++r) {
    float x0 = a0[r], x1 = a1[r];
    for (int o = 32; o; o >>= 1) {
      x0 += __shfl_down(x0, o, 64);
      x1 += __shfl_down(x1, o, 64);
    }
    if ((t & 63) == 0) { sm0[r][t >> 6] = x0; sm1[r][t >> 6] = x1; }
  }
  __syncthreads();
  if (t < 8) {
    logits[(g * 8 + t) * 2] = sm0[t][0] + sm0[t][1] + sm0[t][2] + sm0[t][3] + gb[0];
    logits[(g * 8 + t) * 2 + 1] = sm1[t][0] + sm1[t][1] + sm1[t][2] + sm1[t][3] + gb[1];
  }
}

// ---------------- out[c] = max_i logits[i][c] ----------------
__global__ void maxpool_kernel(const float* __restrict__ logits, float* __restrict__ out) {
  const int t = threadIdx.x;
  float m0 = -3.4e38f, m1 = -3.4e38f;
  for (int i = t; i < NN; i += 256) {
    m0 = fmaxf(m0, logits[i * 2]);
    m1 = fmaxf(m1, logits[i * 2 + 1]);
  }
  for (int o = 32; o; o >>= 1) {
    m0 = fmaxf(m0, __shfl_down(m0, o, 64));
    m1 = fmaxf(m1, __shfl_down(m1, o, 64));
  }
  __shared__ float s0[4], s1[4];
  if ((t & 63) == 0) { s0[t >> 6] = m0; s1[t >> 6] = m1; }
  __syncthreads();
  if (t == 0) {
    out[0] = fmaxf(fmaxf(s0[0], s0[1]), fmaxf(s0[2], s0[3]));
    out[1] = fmaxf(fmaxf(s1[0], s1[1]), fmaxf(s1[2], s1[3]));
  }
}

extern "C" void kernel_launch(void* const* d_in, const int* in_sizes, int n_in,
                              void* d_out, int out_size, void* d_ws, size_t ws_size,
                              hipStream_t stream) {
  (void)in_sizes; (void)n_in; (void)out_size;
  const float* x = (const float*)d_in[0];       // [8192,512]
  const float* adj = (const float*)d_in[1];     // [8192,8192]
  const float* cheb_W = (const float*)d_in[2];  // [3,512,256]
  const float* cheb_b = (const float*)d_in[3];  // [256]
  const float* gc2_W = (const float*)d_in[4];   // [256,2]
  const float* gc2_b = (const float*)d_in[5];   // [2]
  float* out = (float*)d_out;                   // [2]

  char* ws = (char*)d_ws;
  unsigned short* Abf  = (unsigned short*)(ws);               // 128 MiB bf16 adj, live to end
  unsigned short* xbf  = (unsigned short*)(ws + 134217728L);  // 8 MiB
  unsigned short* WTc  = (unsigned short*)(ws + 142606336L);  // 768 KiB [768][512]
  float* Q0            = (float*)(ws + 143392768L);           // 8 MiB f32 [8192][256] = x(W0-W2)
  unsigned short* q12T = (unsigned short*)(ws + 151781376L);  // 8 MiB bf16 [512][8192]
  float* s1            = (float*)(ws + 160169984L);           // 8 MiB f32 [8192][256]
  unsigned short* bT2  = (unsigned short*)(ws + 168558592L);  // 4 MiB bf16 [256][8192]
  float* dinv          = (float*)(ws + 172752896L);           // 32 KiB
  float* v             = (float*)(ws + 172785664L);           // 64 KiB
  float* logits        = (float*)(ws + 172851200L);           // 64 KiB
  unsigned short* P    = (unsigned short*)(ws + 172916736L);  // bf16 split-K partials

  const long PBASE = 172916736L;
  int ksA = 1, ksB = 2; // P: max(8 MiB, 8 MiB)
  if (ws_size >= (size_t)(PBASE + 32L * 1048576L)) { ksA = 4; ksB = 8; }
  else if (ws_size >= (size_t)(PBASE + 16L * 1048576L)) { ksA = 2; ksB = 4; }

  // 1) fused: Abf=bf16(adj)+dinv; xbf=bf16(x); WTc=[W0-W2|W1|W2]^T
  fusedprep_kernel<<<dim3(13824), dim3(256), 0, stream>>>(adj, x, cheb_W, Abf, dinv, xbf, WTc);
  // 2) gemm_w: Q = xbf @ Wcat -> Q0 (f32, cols<256), q12T = (dinv.*[q1|q2])^T bf16
  gemm_w<<<dim3(6, 64, 1), dim3(256), 0, stream>>>(xbf, WTc, 512, 512, 512, 768,
      Q0, q12T, dinv);
  // 3) GEMM_A: P = split-K bf16 partials of Abf @ (dinv.*[q1|q2])  [8192][512]
  gemm8<<<dim3(2, 32, ksA), dim3(512), 0, stream>>>(Abf, q12T, NN / ksA, 512, P);
  // 4) reduceA: s1 = dinv.*S[:,0:256] f32; bT2 = (dinv^2 .* S[:,256:512])^T bf16
  reduceA_kernel<<<dim3(8, 128), dim3(256), 0, stream>>>(P, ksA, dinv, s1, bT2);
  // 5) GEMM_B: P = split-K bf16 partials of Abf @ (dinv.*s2)  [8192][256]
  gemm8<<<dim3(1, 32, ksB), dim3(512), 0, stream>>>(Abf, bT2, NN / ksB, 256, P);
  // 6) h = relu(Q0 - s1 + 2*dinv.*sumP + b); v = h @ gc2_W
  combine_u_kernel<<<dim3(NN), dim3(256), 0, stream>>>(Q0, s1, P, ksB, dinv, cheb_b, gc2_W, v);
  // 7) logits = bf16(adj) @ v + b
  logits8_kernel<<<dim3(1024), dim3(256), 0, stream>>>(Abf, v, gc2_b, logits);
  maxpool_kernel<<<dim3(1), dim3(256), 0, stream>>>(logits, out);
}